// Round 1
// baseline (384.340 us; speedup 1.0000x reference)
//
#include <hip/hip_runtime.h>
#include <math.h>

#define T 2048
#define E 64
#define H 8
#define B 2

// ---------------------------------------------------------------------------
// K1: per-token projections.  qs[b,h,t] = emb[b,t,:]·qk[h,:],  ks likewise,
//     v[b,h,t,f] = sum_e emb[b,t,e]*vk[h,e,f]
// ---------------------------------------------------------------------------
__global__ __launch_bounds__(256) void qkv_kernel(
    const float* __restrict__ emb,   // [B,T,E]
    const float* __restrict__ qk,    // [H,E]
    const float* __restrict__ kk,    // [H,E]
    const float* __restrict__ vk,    // [H,E,E]
    float* __restrict__ qs,          // [B,H,T]
    float* __restrict__ ks,          // [B,H,T]
    float* __restrict__ v)           // [B,H,T,E]
{
    int b = blockIdx.x >> 11;
    int t = blockIdx.x & 2047;
    int tid = threadIdx.x;
    __shared__ float embL[64];
    if (tid < 16) {
        ((float4*)embL)[tid] = ((const float4*)(emb + ((long)b*T + t)*E))[tid];
    }
    __syncthreads();
    if (tid < 16) {
        int h = tid & 7;
        const float* w = (tid < 8) ? qk : kk;
        float s = 0.f;
        #pragma unroll
        for (int e = 0; e < 64; ++e) s += embL[e] * w[h*64 + e];
        float* dst = (tid < 8) ? qs : ks;
        dst[((long)b*H + h)*T + t] = s;
    }
    #pragma unroll
    for (int p = 0; p < 2; ++p) {
        int idx = tid + p*256;           // 0..511 -> (h,f)
        int h = idx >> 6, f = idx & 63;
        float acc = 0.f;
        #pragma unroll
        for (int e = 0; e < 64; ++e)
            acc += embL[e] * vk[(h*64 + e)*64 + f];
        v[(((long)b*H + h)*T + t)*E + f] = acc;
    }
}

// ---------------------------------------------------------------------------
// K2: per-(b,h) min/max of ks  (for exact softmax max: scores are rank-1)
// ---------------------------------------------------------------------------
__global__ __launch_bounds__(256) void minmax_kernel(
    const float* __restrict__ ks, float* __restrict__ kmax, float* __restrict__ kmin)
{
    int bh = blockIdx.x;
    int tid = threadIdx.x;
    float mx = -1e30f, mn = 1e30f;
    for (int i = tid; i < T; i += 256) {
        float x = ks[(long)bh*T + i];
        mx = fmaxf(mx, x); mn = fminf(mn, x);
    }
    __shared__ float smx[256], smn[256];
    smx[tid] = mx; smn[tid] = mn;
    __syncthreads();
    for (int s = 128; s > 0; s >>= 1) {
        if (tid < s) {
            smx[tid] = fmaxf(smx[tid], smx[tid+s]);
            smn[tid] = fminf(smn[tid], smn[tid+s]);
        }
        __syncthreads();
    }
    if (tid == 0) { kmax[bh] = smx[0]; kmin[bh] = smn[0]; }
}

// ---------------------------------------------------------------------------
// K3: attention.  For 32 q-rows of one (b,h):
//     z[q,f] = sum_k exp(s_q*k_k - m_q) * v[k,f] / den_q ;  + emb residual.
// P-tile and V-tile staged in LDS; fp32 FMA inner loop.
// ---------------------------------------------------------------------------
__global__ __launch_bounds__(256) void attn_kernel(
    const float* __restrict__ qs, const float* __restrict__ ksg,
    const float* __restrict__ kmax, const float* __restrict__ kmin,
    const float* __restrict__ v, const float* __restrict__ emb,
    float* __restrict__ zpre)
{
    int bh = blockIdx.x >> 6;            // 0..15
    int q0 = (blockIdx.x & 63) * 32;
    int b  = bh >> 3;
    int tid = threadIdx.x;

    __shared__ float ksL[2048];          // 8 KB
    __shared__ float Vt[128][64];        // 32 KB
    __shared__ float Pt[32][128];        // 16 KB
    __shared__ float sr[32], mr[32];

    for (int i = tid; i < 2048; i += 256) ksL[i] = ksg[(long)bh*T + i];
    if (tid < 32) {
        float s = qs[(long)bh*T + q0 + tid];
        sr[tid] = s;
        mr[tid] = (s >= 0.f) ? s*kmax[bh] : s*kmin[bh];
    }
    __syncthreads();

    int rp = tid >> 4;                   // 0..15
    int f4 = tid & 15;                   // float4 column group
    int r0 = rp*2, r1 = r0 + 1;
    float4 a0 = {0,0,0,0}, a1 = {0,0,0,0};
    float d0 = 0.f, d1 = 0.f;

    for (int kc = 0; kc < 16; ++kc) {
        // stage V chunk [128][64]
        #pragma unroll
        for (int j = 0; j < 8; ++j) {
            int i = tid + j*256;         // float4 slot 0..2047
            int kkk = i >> 4, ff = i & 15;
            ((float4*)&Vt[kkk][0])[ff] =
                ((const float4*)(v + (((long)bh*T) + kc*128 + kkk)*E))[ff];
        }
        // compute P tile [32][128]
        #pragma unroll
        for (int j = 0; j < 16; ++j) {
            int i = tid + j*256;         // 0..4095
            int r = i >> 7, k = i & 127;
            Pt[r][k] = __expf(sr[r]*ksL[kc*128 + k] - mr[r]);
        }
        __syncthreads();
        #pragma unroll 4
        for (int k = 0; k < 128; ++k) {
            float p0 = Pt[r0][k], p1 = Pt[r1][k];
            float4 vv = ((float4*)&Vt[k][0])[f4];
            a0.x += p0*vv.x; a0.y += p0*vv.y; a0.z += p0*vv.z; a0.w += p0*vv.w;
            a1.x += p1*vv.x; a1.y += p1*vv.y; a1.z += p1*vv.z; a1.w += p1*vv.w;
            d0 += p0; d1 += p1;
        }
        __syncthreads();
    }

    float inv0 = 1.f/d0, inv1 = 1.f/d1;
    float4 e0 = ((const float4*)(emb + (((long)b*T) + q0 + r0)*E))[f4];
    float4 e1 = ((const float4*)(emb + (((long)b*T) + q0 + r1)*E))[f4];
    float4 o0, o1;
    o0.x = e0.x + a0.x*inv0; o0.y = e0.y + a0.y*inv0;
    o0.z = e0.z + a0.z*inv0; o0.w = e0.w + a0.w*inv0;
    o1.x = e1.x + a1.x*inv1; o1.y = e1.y + a1.y*inv1;
    o1.z = e1.z + a1.z*inv1; o1.w = e1.w + a1.w*inv1;
    ((float4*)(zpre + (((long)bh*T) + q0 + r0)*E))[f4] = o0;
    ((float4*)(zpre + (((long)bh*T) + q0 + r1)*E))[f4] = o1;
}

// ---------------------------------------------------------------------------
// K4: LN1 -> cross-head FFN (512x512 per token) -> +residual -> gelu -> LN2
// Block handles 8 tokens of one batch; W streamed through LDS in 32-row chunks.
// ---------------------------------------------------------------------------
__global__ __launch_bounds__(256) void ffn_kernel(
    const float* __restrict__ zpre,  // [B,H,T,E]
    const float* __restrict__ fk,    // [H,G,E,F]
    const float* __restrict__ g1, const float* __restrict__ b1,
    const float* __restrict__ g2, const float* __restrict__ b2,
    float* __restrict__ out)         // [B,G,T,F]
{
    int b  = blockIdx.x >> 8;
    int t0 = (blockIdx.x & 255) * 8;
    int tid = threadIdx.x;

    __shared__ float znL[8][512];    // 16 KB  (LN1 output, also residual)
    __shared__ float WL[32][512];    // 64 KB  (W chunk; reused as yL later)

    // load zpre for 8 tokens x 8 heads x 64
    #pragma unroll
    for (int j = 0; j < 4; ++j) {
        int i = tid + j*256;         // float4 slot 0..1023
        int h = i >> 7, tt = (i >> 4) & 7, e4 = i & 15;
        ((float4*)&znL[tt][h*64])[e4] =
            ((const float4*)(zpre + ((((long)b*H + h)*T) + t0 + tt)*E))[e4];
    }
    __syncthreads();

    // LN1 per (token,head) row of 64, in place
    if (tid < 64) {
        int tt = tid >> 3, h = tid & 7;
        float* row = &znL[tt][h*64];
        int st = tid & 63;           // stagger to dodge bank conflicts
        float mu = 0.f;
        for (int e = 0; e < 64; ++e) mu += row[(st+e)&63];
        mu *= (1.f/64.f);
        float var = 0.f;
        for (int e = 0; e < 64; ++e) { float d = row[(st+e)&63] - mu; var += d*d; }
        var *= (1.f/64.f);
        float rs = rsqrtf(var + 1e-3f);
        for (int e = 0; e < 64; ++e) {
            int ei = (st+e)&63;
            row[ei] = g1[ei]*(row[ei]-mu)*rs + b1[ei];
        }
    }
    __syncthreads();

    // FFN: y[token][c] = sum_ke zn[token][ke] * W[ke][c]
    int tt = tid >> 5;               // token 0..7
    int c0s = tid & 31;              // float4 col slot base
    float4 acc[4];
    #pragma unroll
    for (int j = 0; j < 4; ++j) acc[j] = make_float4(0.f,0.f,0.f,0.f);

    for (int kc = 0; kc < 16; ++kc) {
        // stage W chunk [32 ke][512 c]
        #pragma unroll
        for (int j = 0; j < 16; ++j) {
            int i = tid + j*256;     // float4 slot 0..4095
            int kel = i >> 7;        // 0..31
            int c4  = i & 127;       // float4 col
            int ke = kc*32 + kel;
            int h = ke >> 6, e = ke & 63;
            int g = c4 >> 4, f4 = c4 & 15;
            ((float4*)&WL[kel][0])[c4] =
                ((const float4*)(fk + (((long)(h*8 + g)*64 + e)*64)))[f4];
        }
        __syncthreads();
        #pragma unroll 8
        for (int kel = 0; kel < 32; ++kel) {
            float zs = znL[tt][kc*32 + kel];
            #pragma unroll
            for (int j = 0; j < 4; ++j) {
                float4 w = ((float4*)&WL[kel][0])[c0s + 32*j];
                acc[j].x += zs*w.x; acc[j].y += zs*w.y;
                acc[j].z += zs*w.z; acc[j].w += zs*w.w;
            }
        }
        __syncthreads();
    }

    // residual + gelu(tanh approx) -> yL (reuse WL)
    float* yL = &WL[0][0];
    const float kg = 0.7978845608028654f;  // sqrt(2/pi)
    #pragma unroll
    for (int j = 0; j < 4; ++j) {
        int cbase = (c0s + 32*j)*4;
        float4 z4 = *(const float4*)&znL[tt][cbase];
        float y[4] = { z4.x + acc[j].x, z4.y + acc[j].y,
                       z4.z + acc[j].z, z4.w + acc[j].w };
        float4 o;
        float* op = &o.x;
        #pragma unroll
        for (int q = 0; q < 4; ++q) {
            float x = y[q];
            op[q] = 0.5f*x*(1.f + tanhf(kg*(x + 0.044715f*x*x*x)));
        }
        *(float4*)&yL[tt*512 + cbase] = o;
    }
    __syncthreads();

    // LN2 per (token, g) row of 64, in place
    if (tid < 64) {
        int tt2 = tid >> 3, g = tid & 7;
        float* row = &yL[tt2*512 + g*64];
        int st = tid & 63;
        float mu = 0.f;
        for (int e = 0; e < 64; ++e) mu += row[(st+e)&63];
        mu *= (1.f/64.f);
        float var = 0.f;
        for (int e = 0; e < 64; ++e) { float d = row[(st+e)&63] - mu; var += d*d; }
        var *= (1.f/64.f);
        float rs = rsqrtf(var + 1e-3f);
        for (int e = 0; e < 64; ++e) {
            int ei = (st+e)&63;
            row[ei] = g2[ei]*(row[ei]-mu)*rs + b2[ei];
        }
    }
    __syncthreads();

    // coalesced store
    #pragma unroll
    for (int j = 0; j < 4; ++j) {
        int i = tid + j*256;
        int g = i >> 7, tt3 = (i >> 4) & 7, e4 = i & 15;
        ((float4*)(out + ((((long)b*H + g)*T) + t0 + tt3)*E))[e4] =
            ((float4*)&yL[tt3*512 + g*64])[e4];
    }
}

// ---------------------------------------------------------------------------
extern "C" void kernel_launch(void* const* d_in, const int* in_sizes, int n_in,
                              void* d_out, int out_size, void* d_ws, size_t ws_size,
                              hipStream_t stream) {
    const float* emb  = (const float*)d_in[0];   // [B,T,E]
    const float* keyk = (const float*)d_in[1];   // [1,H,E]
    const float* qryk = (const float*)d_in[2];   // [1,H,E]
    const float* valk = (const float*)d_in[3];   // [1,H,E,E]
    const float* ffk  = (const float*)d_in[4];   // [1,H,H,E,E]
    const float* g1   = (const float*)d_in[5];
    const float* b1   = (const float*)d_in[6];
    const float* g2   = (const float*)d_in[7];
    const float* b2   = (const float*)d_in[8];
    float* out = (float*)d_out;

    float* ws   = (float*)d_ws;
    float* qs   = ws;                    // 32768
    float* ks   = ws + 32768;            // 32768
    float* kmx  = ws + 65536;            // 16
    float* kmn  = ws + 65552;            // 16
    float* v    = ws + 65568;            // 2097152
    float* zpre = ws + 65568 + 2097152;  // 2097152

    qkv_kernel<<<B*T, 256, 0, stream>>>(emb, qryk, keyk, valk, qs, ks, v);
    minmax_kernel<<<B*H, 256, 0, stream>>>(ks, kmx, kmn);
    attn_kernel<<<B*H*(T/32), 256, 0, stream>>>(qs, ks, kmx, kmn, v, emb, zpre);
    ffn_kernel<<<B*(T/8), 256, 0, stream>>>(zpre, ffk, g1, b1, g2, b2, out);
}

// Round 4
// 258.410 us; speedup vs baseline: 1.4873x; 1.4873x over previous
//
#include <hip/hip_runtime.h>
#include <math.h>

#define T 2048
#define E 64
#define H 8
#define B 2

typedef __attribute__((ext_vector_type(4))) float f32x4;
typedef __attribute__((ext_vector_type(8))) short s16x8;

static __device__ __forceinline__ unsigned short f2bf(float x) {
    union { float f; unsigned u; } v; v.f = x;
    unsigned r = v.u + 0x7FFFu + ((v.u >> 16) & 1u);   // RNE
    return (unsigned short)(r >> 16);
}

// ---------------------------------------------------------------------------
// K1: per-token projections. qs/ks fp32 [bh][t]; V written TRANSPOSED bf16:
//     vT[bh][f][t]  so attention can stage V^T rows (k-contiguous) coalesced.
// ---------------------------------------------------------------------------
__global__ __launch_bounds__(256) void qkvT_kernel(
    const float* __restrict__ emb,   // [B,T,E]
    const float* __restrict__ qk,    // [H,E]
    const float* __restrict__ kk,    // [H,E]
    const float* __restrict__ vk,    // [H,E,E]
    float* __restrict__ qs,          // [B*H,T]
    float* __restrict__ ks,          // [B*H,T]
    unsigned short* __restrict__ vT) // [B*H,E(f),T] bf16
{
    int b  = blockIdx.x >> 7;
    int t0 = (blockIdx.x & 127) * 16;
    int tid = threadIdx.x;

    __shared__ __align__(16) float eL[16][64];   // 4 KB
    __shared__ __align__(16) float wL[1024];     // qk | kk, 4 KB

    ((float4*)eL)[tid] = ((const float4*)(emb + ((long)b*T + t0)*E))[tid];
    ((float4*)wL)[tid & 255] = (tid < 128) ? ((const float4*)qk)[tid]
                                           : ((const float4*)kk)[tid - 128];
    __syncthreads();

    // ---- scores: 16 tokens x (8 q + 8 k) dots of length 64
    {
        int tl = tid >> 4, sc = tid & 15;
        int h = sc & 7, sel = sc >> 3;           // sel=0 -> q, 1 -> k
        const float* wp = wL + sel*512 + h*64;
        float s = 0.f;
        #pragma unroll
        for (int e = 0; e < 64; ++e) {
            int ei = (e + sc*4) & 63;            // stagger banks
            s += eL[tl][ei] * wp[ei];
        }
        float* dst = sel ? ks : qs;
        dst[((long)b*H + h)*T + t0 + tl] = s;
    }

    // ---- V projection: thread -> 2 (h,f) pairs, 16 tokens each
    #pragma unroll
    for (int p = 0; p < 2; ++p) {
        int hf = tid + p*256;
        int h = hf >> 6, f = hf & 63;
        float acc[16];
        #pragma unroll
        for (int t = 0; t < 16; ++t) acc[t] = 0.f;
        #pragma unroll 4
        for (int e = 0; e < 64; ++e) {
            float w = vk[(h*64 + e)*64 + f];     // coalesced across lanes
            #pragma unroll
            for (int t = 0; t < 16; ++t) acc[t] += eL[t][e] * w;  // LDS broadcast
        }
        long row = ((long)(b*H + h)*64 + f) * (long)T;
        s16x8 o0, o1;
        #pragma unroll
        for (int t = 0; t < 8; ++t) { o0[t] = (short)f2bf(acc[t]); o1[t] = (short)f2bf(acc[t+8]); }
        *(s16x8*)(vT + row + t0)     = o0;
        *(s16x8*)(vT + row + t0 + 8) = o1;
    }
}

// ---------------------------------------------------------------------------
// K2: per-(b,h) min/max of ks (exact softmax max for rank-1 scores)
// ---------------------------------------------------------------------------
__global__ __launch_bounds__(256) void minmax_kernel(
    const float* __restrict__ ks, float* __restrict__ kmax, float* __restrict__ kmin)
{
    int bh = blockIdx.x;
    int tid = threadIdx.x;
    float mx = -1e30f, mn = 1e30f;
    for (int i = tid; i < T; i += 256) {
        float x = ks[(long)bh*T + i];
        mx = fmaxf(mx, x); mn = fminf(mn, x);
    }
    __shared__ float smx[256], smn[256];
    smx[tid] = mx; smn[tid] = mn;
    __syncthreads();
    for (int s = 128; s > 0; s >>= 1) {
        if (tid < s) {
            smx[tid] = fmaxf(smx[tid], smx[tid+s]);
            smn[tid] = fminf(smn[tid], smn[tid+s]);
        }
        __syncthreads();
    }
    if (tid == 0) { kmax[bh] = smx[0]; kmin[bh] = smn[0]; }
}

// ---------------------------------------------------------------------------
// K3: attention via MFMA.  Block = (bh, 32 q-rows). 4 waves:
//   wave w: row-tile rt=w>>1 (16 rows), col-tiles ct0=(w&1)*2 .. +1.
// A (P, bf16) built in-register: p = exp(s_q*k - m_q); B = V^T rows from
// swizzled LDS. Denominator: per-lane fp32 sums + shfl reduce; broadcast
// to output rows via width-16 shfl (NO shared state, register-only epilogue).
// ---------------------------------------------------------------------------
__global__ __launch_bounds__(256) void attn_kernel(
    const float* __restrict__ qs, const float* __restrict__ ksg,
    const float* __restrict__ kmax, const float* __restrict__ kmin,
    const unsigned short* __restrict__ vT, const float* __restrict__ emb,
    float* __restrict__ zpre)
{
    int bh = blockIdx.x >> 6;            // 0..15
    int q0 = (blockIdx.x & 63) * 32;
    int b  = bh >> 3;
    int tid = threadIdx.x;
    int w = tid >> 6, l = tid & 63;
    int g = l >> 4, r = l & 15;
    int rt = w >> 1, ct0 = (w & 1) * 2;

    __shared__ __align__(16) float ksL[2048];           // 8 KB
    __shared__ __align__(16) unsigned short VtL[8192];  // [64 f][128 k] bf16, swizzled, 16 KB

    ((float4*)ksL)[tid]       = ((const float4*)(ksg + (long)bh*T))[tid];
    ((float4*)ksL)[tid + 256] = ((const float4*)(ksg + (long)bh*T))[tid + 256];

    float sreg, mreg;
    {
        float s = qs[(long)bh*T + q0 + rt*16 + r];
        sreg = s;
        mreg = (s >= 0.f) ? s*kmax[bh] : s*kmin[bh];
    }
    __syncthreads();                     // ksL visible to all waves

    f32x4 acc0 = {0.f,0.f,0.f,0.f}, acc1 = {0.f,0.f,0.f,0.f};
    float dsum = 0.f;

    for (int kc = 0; kc < 16; ++kc) {
        // stage V^T chunk [64 f][128 k] bf16, 16B-slot swizzle: slot ^= f&15
        #pragma unroll
        for (int j = 0; j < 4; ++j) {
            int i = tid + j*256;         // 16B-slot 0..1023
            int f = i >> 4, s16 = i & 15;
            s16x8 val = *(const s16x8*)(vT + ((long)(bh*64 + f))*T + kc*128 + s16*8);
            *(s16x8*)&VtL[f*128 + ((s16 ^ (f & 15)) * 8)] = val;
        }
        __syncthreads();                 // staging visible
        #pragma unroll
        for (int kw = 0; kw < 4; ++kw) { // 32-k MFMA windows
            int kbase = kc*128 + kw*32 + g*8;
            float4 ka = *(const float4*)&ksL[kbase];
            float4 kb = *(const float4*)&ksL[kbase + 4];
            float p0 = __expf(fmaf(sreg, ka.x, -mreg));
            float p1 = __expf(fmaf(sreg, ka.y, -mreg));
            float p2 = __expf(fmaf(sreg, ka.z, -mreg));
            float p3 = __expf(fmaf(sreg, ka.w, -mreg));
            float p4 = __expf(fmaf(sreg, kb.x, -mreg));
            float p5 = __expf(fmaf(sreg, kb.y, -mreg));
            float p6 = __expf(fmaf(sreg, kb.z, -mreg));
            float p7 = __expf(fmaf(sreg, kb.w, -mreg));
            dsum += ((p0+p1)+(p2+p3)) + ((p4+p5)+(p6+p7));
            s16x8 af;
            af[0] = (short)f2bf(p0); af[1] = (short)f2bf(p1);
            af[2] = (short)f2bf(p2); af[3] = (short)f2bf(p3);
            af[4] = (short)f2bf(p4); af[5] = (short)f2bf(p5);
            af[6] = (short)f2bf(p6); af[7] = (short)f2bf(p7);
            int slot = kw*4 + g;
            s16x8 bf0 = *(const s16x8*)&VtL[(ct0*16 + r)*128     + ((slot ^ r) * 8)];
            s16x8 bf1 = *(const s16x8*)&VtL[((ct0+1)*16 + r)*128 + ((slot ^ r) * 8)];
            acc0 = __builtin_amdgcn_mfma_f32_16x16x32_bf16(af, bf0, acc0, 0, 0, 0);
            acc1 = __builtin_amdgcn_mfma_f32_16x16x32_bf16(af, bf1, acc1, 0, 0, 0);
        }
        __syncthreads();                 // compute done before next staging
    }

    // full row-denominator into every lane of the 4 k-slot group
    dsum += __shfl_xor(dsum, 16, 64);
    dsum += __shfl_xor(dsum, 32, 64);
    // lane (g, r) holds denom of local row r; output rows need g*4+i.

    #pragma unroll
    for (int i = 0; i < 4; ++i) {
        int lrow = g*4 + i;               // C layout: local row=(lane>>4)*4+i
        float den = __shfl(dsum, lrow, 16);  // src lane = 16*g + lrow (holds row lrow)
        float inv = 1.f / den;
        long q = q0 + rt*16 + lrow;
        int f0 = ct0*16 + r, f1 = f0 + 16;
        float e0 = emb[((long)b*T + q)*E + f0];
        float e1 = emb[((long)b*T + q)*E + f1];
        zpre[((long)bh*T + q)*E + f0] = e0 + acc0[i] * inv;
        zpre[((long)bh*T + q)*E + f1] = e1 + acc1[i] * inv;
    }
}

// ---------------------------------------------------------------------------
// K4: LN1 -> cross-head FFN (512x512 per token) -> +residual -> gelu -> LN2
// (unchanged; passed post-timing in round 1)
// ---------------------------------------------------------------------------
__global__ __launch_bounds__(256) void ffn_kernel(
    const float* __restrict__ zpre,  // [B,H,T,E]
    const float* __restrict__ fk,    // [H,G,E,F]
    const float* __restrict__ g1, const float* __restrict__ b1,
    const float* __restrict__ g2, const float* __restrict__ b2,
    float* __restrict__ out)         // [B,G,T,F]
{
    int b  = blockIdx.x >> 8;
    int t0 = (blockIdx.x & 255) * 8;
    int tid = threadIdx.x;

    __shared__ float znL[8][512];    // 16 KB
    __shared__ float WL[32][512];    // 64 KB

    #pragma unroll
    for (int j = 0; j < 4; ++j) {
        int i = tid + j*256;
        int h = i >> 7, tt = (i >> 4) & 7, e4 = i & 15;
        ((float4*)&znL[tt][h*64])[e4] =
            ((const float4*)(zpre + ((((long)b*H + h)*T) + t0 + tt)*E))[e4];
    }
    __syncthreads();

    if (tid < 64) {
        int tt = tid >> 3, h = tid & 7;
        float* row = &znL[tt][h*64];
        int st = tid & 63;
        float mu = 0.f;
        for (int e = 0; e < 64; ++e) mu += row[(st+e)&63];
        mu *= (1.f/64.f);
        float var = 0.f;
        for (int e = 0; e < 64; ++e) { float d = row[(st+e)&63] - mu; var += d*d; }
        var *= (1.f/64.f);
        float rs = rsqrtf(var + 1e-3f);
        for (int e = 0; e < 64; ++e) {
            int ei = (st+e)&63;
            row[ei] = g1[ei]*(row[ei]-mu)*rs + b1[ei];
        }
    }
    __syncthreads();

    int tt = tid >> 5;
    int c0s = tid & 31;
    float4 acc[4];
    #pragma unroll
    for (int j = 0; j < 4; ++j) acc[j] = make_float4(0.f,0.f,0.f,0.f);

    for (int kc = 0; kc < 16; ++kc) {
        #pragma unroll
        for (int j = 0; j < 16; ++j) {
            int i = tid + j*256;
            int kel = i >> 7;
            int c4  = i & 127;
            int ke = kc*32 + kel;
            int h = ke >> 6, e = ke & 63;
            int g = c4 >> 4, f4 = c4 & 15;
            ((float4*)&WL[kel][0])[c4] =
                ((const float4*)(fk + (((long)(h*8 + g)*64 + e)*64)))[f4];
        }
        __syncthreads();
        #pragma unroll 8
        for (int kel = 0; kel < 32; ++kel) {
            float zs = znL[tt][kc*32 + kel];
            #pragma unroll
            for (int j = 0; j < 4; ++j) {
                float4 w = ((float4*)&WL[kel][0])[c0s + 32*j];
                acc[j].x += zs*w.x; acc[j].y += zs*w.y;
                acc[j].z += zs*w.z; acc[j].w += zs*w.w;
            }
        }
        __syncthreads();
    }

    float* yL = &WL[0][0];
    const float kg = 0.7978845608028654f;
    #pragma unroll
    for (int j = 0; j < 4; ++j) {
        int cbase = (c0s + 32*j)*4;
        float4 z4 = *(const float4*)&znL[tt][cbase];
        float y[4] = { z4.x + acc[j].x, z4.y + acc[j].y,
                       z4.z + acc[j].z, z4.w + acc[j].w };
        float4 o;
        float* op = &o.x;
        #pragma unroll
        for (int q = 0; q < 4; ++q) {
            float x = y[q];
            op[q] = 0.5f*x*(1.f + tanhf(kg*(x + 0.044715f*x*x*x)));
        }
        *(float4*)&yL[tt*512 + cbase] = o;
    }
    __syncthreads();

    if (tid < 64) {
        int tt2 = tid >> 3, g = tid & 7;
        float* row = &yL[tt2*512 + g*64];
        int st = tid & 63;
        float mu = 0.f;
        for (int e = 0; e < 64; ++e) mu += row[(st+e)&63];
        mu *= (1.f/64.f);
        float var = 0.f;
        for (int e = 0; e < 64; ++e) { float d = row[(st+e)&63] - mu; var += d*d; }
        var *= (1.f/64.f);
        float rs = rsqrtf(var + 1e-3f);
        for (int e = 0; e < 64; ++e) {
            int ei = (st+e)&63;
            row[ei] = g2[ei]*(row[ei]-mu)*rs + b2[ei];
        }
    }
    __syncthreads();

    #pragma unroll
    for (int j = 0; j < 4; ++j) {
        int i = tid + j*256;
        int g = i >> 7, tt3 = (i >> 4) & 7, e4 = i & 15;
        ((float4*)(out + ((((long)b*H + g)*T) + t0 + tt3)*E))[e4] =
            ((float4*)&yL[tt3*512 + g*64])[e4];
    }
}

// ---------------------------------------------------------------------------
extern "C" void kernel_launch(void* const* d_in, const int* in_sizes, int n_in,
                              void* d_out, int out_size, void* d_ws, size_t ws_size,
                              hipStream_t stream) {
    const float* emb  = (const float*)d_in[0];
    const float* keyk = (const float*)d_in[1];
    const float* qryk = (const float*)d_in[2];
    const float* valk = (const float*)d_in[3];
    const float* ffk  = (const float*)d_in[4];
    const float* g1   = (const float*)d_in[5];
    const float* b1   = (const float*)d_in[6];
    const float* g2   = (const float*)d_in[7];
    const float* b2   = (const float*)d_in[8];
    float* out = (float*)d_out;

    float* ws   = (float*)d_ws;
    float* qs   = ws;                         // 32768
    float* ks   = ws + 32768;                 // 32768
    float* kmx  = ws + 65536;                 // 16
    float* kmn  = ws + 65552;                 // 16
    unsigned short* vT = (unsigned short*)(ws + 65568);   // 2,097,152 bf16
    float* zpre = ws + 65568 + 1048576;       // 2,097,152 floats

    qkvT_kernel<<<B*T/16, 256, 0, stream>>>(emb, qryk, keyk, valk, qs, ks, vT);
    minmax_kernel<<<B*H, 256, 0, stream>>>(ks, kmx, kmn);
    attn_kernel<<<B*H*(T/32), 256, 0, stream>>>(qs, ks, kmx, kmn, vT, emb, zpre);
    ffn_kernel<<<B*(T/8), 256, 0, stream>>>(zpre, ffk, g1, b1, g2, b2, out);
}

// Round 6
// 112.933 us; speedup vs baseline: 3.4032x; 2.2882x over previous
//
#include <hip/hip_runtime.h>
#include <math.h>

#define T 2048
#define E 64
#define H 8
#define B 2

typedef __attribute__((ext_vector_type(4))) float f32x4;
typedef __attribute__((ext_vector_type(8))) short s16x8;

static __device__ __forceinline__ unsigned short f2bf(float x) {
    union { float f; unsigned u; } v; v.f = x;
    unsigned r = v.u + 0x7FFFu + ((v.u >> 16) & 1u);   // RNE
    return (unsigned short)(r >> 16);
}
static __device__ __forceinline__ float bf2f(unsigned short u) {
    union { unsigned u; float f; } v; v.u = ((unsigned)u) << 16;
    return v.f;
}

// ---------------------------------------------------------------------------
// K1: per-token projections. qs/ks fp32 [bh][t]; V written TRANSPOSED bf16:
//     vT[bh][f][t]  so attention can stage V^T rows (k-contiguous) coalesced.
// ---------------------------------------------------------------------------
__global__ __launch_bounds__(256) void qkvT_kernel(
    const float* __restrict__ emb,   // [B,T,E]
    const float* __restrict__ qk,    // [H,E]
    const float* __restrict__ kk,    // [H,E]
    const float* __restrict__ vk,    // [H,E,E]
    float* __restrict__ qs,          // [B*H,T]
    float* __restrict__ ks,          // [B*H,T]
    unsigned short* __restrict__ vT) // [B*H,E(f),T] bf16
{
    int b  = blockIdx.x >> 7;
    int t0 = (blockIdx.x & 127) * 16;
    int tid = threadIdx.x;

    __shared__ __align__(16) float eL[16][64];   // 4 KB
    __shared__ __align__(16) float wL[1024];     // qk | kk, 4 KB

    ((float4*)eL)[tid] = ((const float4*)(emb + ((long)b*T + t0)*E))[tid];
    ((float4*)wL)[tid & 255] = (tid < 128) ? ((const float4*)qk)[tid]
                                           : ((const float4*)kk)[tid - 128];
    __syncthreads();

    // ---- scores: 16 tokens x (8 q + 8 k) dots of length 64
    {
        int tl = tid >> 4, sc = tid & 15;
        int h = sc & 7, sel = sc >> 3;           // sel=0 -> q, 1 -> k
        const float* wp = wL + sel*512 + h*64;
        float s = 0.f;
        #pragma unroll
        for (int e = 0; e < 64; ++e) {
            int ei = (e + sc*4) & 63;            // stagger banks
            s += eL[tl][ei] * wp[ei];
        }
        float* dst = sel ? ks : qs;
        dst[((long)b*H + h)*T + t0 + tl] = s;
    }

    // ---- V projection: thread -> 2 (h,f) pairs, 16 tokens each
    #pragma unroll
    for (int p = 0; p < 2; ++p) {
        int hf = tid + p*256;
        int h = hf >> 6, f = hf & 63;
        float acc[16];
        #pragma unroll
        for (int t = 0; t < 16; ++t) acc[t] = 0.f;
        #pragma unroll 4
        for (int e = 0; e < 64; ++e) {
            float w = vk[(h*64 + e)*64 + f];     // coalesced across lanes
            #pragma unroll
            for (int t = 0; t < 16; ++t) acc[t] += eL[t][e] * w;  // LDS broadcast
        }
        long row = ((long)(b*H + h)*64 + f) * (long)T;
        s16x8 o0, o1;
        #pragma unroll
        for (int t = 0; t < 8; ++t) { o0[t] = (short)f2bf(acc[t]); o1[t] = (short)f2bf(acc[t+8]); }
        *(s16x8*)(vT + row + t0)     = o0;
        *(s16x8*)(vT + row + t0 + 8) = o1;
    }
}

// ---------------------------------------------------------------------------
// K2: per-(b,h) min/max of ks (exact softmax max for rank-1 scores)
// ---------------------------------------------------------------------------
__global__ __launch_bounds__(256) void minmax_kernel(
    const float* __restrict__ ks, float* __restrict__ kmax, float* __restrict__ kmin)
{
    int bh = blockIdx.x;
    int tid = threadIdx.x;
    float mx = -1e30f, mn = 1e30f;
    for (int i = tid; i < T; i += 256) {
        float x = ks[(long)bh*T + i];
        mx = fmaxf(mx, x); mn = fminf(mn, x);
    }
    __shared__ float smx[256], smn[256];
    smx[tid] = mx; smn[tid] = mn;
    __syncthreads();
    for (int s = 128; s > 0; s >>= 1) {
        if (tid < s) {
            smx[tid] = fmaxf(smx[tid], smx[tid+s]);
            smn[tid] = fminf(smn[tid], smn[tid+s]);
        }
        __syncthreads();
    }
    if (tid == 0) { kmax[bh] = smx[0]; kmin[bh] = smn[0]; }
}

// ---------------------------------------------------------------------------
// K3: attention via MFMA (unchanged — passed post-timing in round 4).
// ---------------------------------------------------------------------------
__global__ __launch_bounds__(256) void attn_kernel(
    const float* __restrict__ qs, const float* __restrict__ ksg,
    const float* __restrict__ kmax, const float* __restrict__ kmin,
    const unsigned short* __restrict__ vT, const float* __restrict__ emb,
    float* __restrict__ zpre)
{
    int bh = blockIdx.x >> 6;            // 0..15
    int q0 = (blockIdx.x & 63) * 32;
    int b  = bh >> 3;
    int tid = threadIdx.x;
    int w = tid >> 6, l = tid & 63;
    int g = l >> 4, r = l & 15;
    int rt = w >> 1, ct0 = (w & 1) * 2;

    __shared__ __align__(16) float ksL[2048];           // 8 KB
    __shared__ __align__(16) unsigned short VtL[8192];  // [64 f][128 k] bf16, swizzled, 16 KB

    ((float4*)ksL)[tid]       = ((const float4*)(ksg + (long)bh*T))[tid];
    ((float4*)ksL)[tid + 256] = ((const float4*)(ksg + (long)bh*T))[tid + 256];

    float sreg, mreg;
    {
        float s = qs[(long)bh*T + q0 + rt*16 + r];
        sreg = s;
        mreg = (s >= 0.f) ? s*kmax[bh] : s*kmin[bh];
    }
    __syncthreads();                     // ksL visible to all waves

    f32x4 acc0 = {0.f,0.f,0.f,0.f}, acc1 = {0.f,0.f,0.f,0.f};
    float dsum = 0.f;

    for (int kc = 0; kc < 16; ++kc) {
        // stage V^T chunk [64 f][128 k] bf16, 16B-slot swizzle: slot ^= f&15
        #pragma unroll
        for (int j = 0; j < 4; ++j) {
            int i = tid + j*256;         // 16B-slot 0..1023
            int f = i >> 4, s16 = i & 15;
            s16x8 val = *(const s16x8*)(vT + ((long)(bh*64 + f))*T + kc*128 + s16*8);
            *(s16x8*)&VtL[f*128 + ((s16 ^ (f & 15)) * 8)] = val;
        }
        __syncthreads();                 // staging visible
        #pragma unroll
        for (int kw = 0; kw < 4; ++kw) { // 32-k MFMA windows
            int kbase = kc*128 + kw*32 + g*8;
            float4 ka = *(const float4*)&ksL[kbase];
            float4 kb = *(const float4*)&ksL[kbase + 4];
            float p0 = __expf(fmaf(sreg, ka.x, -mreg));
            float p1 = __expf(fmaf(sreg, ka.y, -mreg));
            float p2 = __expf(fmaf(sreg, ka.z, -mreg));
            float p3 = __expf(fmaf(sreg, ka.w, -mreg));
            float p4 = __expf(fmaf(sreg, kb.x, -mreg));
            float p5 = __expf(fmaf(sreg, kb.y, -mreg));
            float p6 = __expf(fmaf(sreg, kb.z, -mreg));
            float p7 = __expf(fmaf(sreg, kb.w, -mreg));
            dsum += ((p0+p1)+(p2+p3)) + ((p4+p5)+(p6+p7));
            s16x8 af;
            af[0] = (short)f2bf(p0); af[1] = (short)f2bf(p1);
            af[2] = (short)f2bf(p2); af[3] = (short)f2bf(p3);
            af[4] = (short)f2bf(p4); af[5] = (short)f2bf(p5);
            af[6] = (short)f2bf(p6); af[7] = (short)f2bf(p7);
            int slot = kw*4 + g;
            s16x8 bf0 = *(const s16x8*)&VtL[(ct0*16 + r)*128     + ((slot ^ r) * 8)];
            s16x8 bf1 = *(const s16x8*)&VtL[((ct0+1)*16 + r)*128 + ((slot ^ r) * 8)];
            acc0 = __builtin_amdgcn_mfma_f32_16x16x32_bf16(af, bf0, acc0, 0, 0, 0);
            acc1 = __builtin_amdgcn_mfma_f32_16x16x32_bf16(af, bf1, acc1, 0, 0, 0);
        }
        __syncthreads();                 // compute done before next staging
    }

    // full row-denominator into every lane of the 4 k-slot group
    dsum += __shfl_xor(dsum, 16, 64);
    dsum += __shfl_xor(dsum, 32, 64);

    #pragma unroll
    for (int i = 0; i < 4; ++i) {
        int lrow = g*4 + i;               // C layout: local row=(lane>>4)*4+i
        float den = __shfl(dsum, lrow, 16);
        float inv = 1.f / den;
        long q = q0 + rt*16 + lrow;
        int f0 = ct0*16 + r, f1 = f0 + 16;
        float e0 = emb[((long)b*T + q)*E + f0];
        float e1 = emb[((long)b*T + q)*E + f1];
        zpre[((long)bh*T + q)*E + f0] = e0 + acc0[i] * inv;
        zpre[((long)bh*T + q)*E + f1] = e1 + acc1[i] * inv;
    }
}

// ---------------------------------------------------------------------------
// K4a: LN1 over zpre rows of 64, output Z bf16 in GEMM layout:
//      Zb[token = b*T+t][h*64+e].  Wave per row, shfl butterfly reduce.
// ---------------------------------------------------------------------------
__global__ __launch_bounds__(256) void ln1_kernel(
    const float* __restrict__ zpre,  // [B*H,T,64]
    const float* __restrict__ g1, const float* __restrict__ b1,
    unsigned short* __restrict__ Zb) // [B*T,512] bf16
{
    int row  = blockIdx.x*4 + (threadIdx.x >> 6);  // bh*T + t, 0..32767
    int lane = threadIdx.x & 63;
    float x = zpre[(long)row*64 + lane];
    float s = x, s2 = x*x;
    #pragma unroll
    for (int o = 1; o < 64; o <<= 1) {
        s  += __shfl_xor(s,  o, 64);
        s2 += __shfl_xor(s2, o, 64);
    }
    float mu  = s * (1.f/64.f);
    float var = s2 * (1.f/64.f) - mu*mu;
    float rs  = rsqrtf(var + 1e-3f);
    float zn  = g1[lane]*(x - mu)*rs + b1[lane];
    int b = row >> 14, h = (row >> 11) & 7, t = row & 2047;
    long token = (long)b*T + t;
    Zb[token*512 + h*64 + lane] = f2bf(zn);
}

// ---------------------------------------------------------------------------
// K4b: weight transpose+cast: fk[h,g,e,f] fp32 -> WbT[n=g*64+f][k=h*64+e] bf16
// ---------------------------------------------------------------------------
__global__ __launch_bounds__(256) void wcvt_kernel(
    const float* __restrict__ fk, unsigned short* __restrict__ WbT)
{
    int hg = blockIdx.x;                 // h*8+g
    int h = hg >> 3, g = hg & 7;
    int tid = threadIdx.x;
    __shared__ float wt[64][65];         // padded, 16.6 KB
    const float* src = fk + (long)hg*4096;
    #pragma unroll
    for (int j = 0; j < 4; ++j) {
        int s = tid + j*256;             // float4 slot 0..1023
        int e = s >> 4, f4 = s & 15;
        float4 v = ((const float4*)src)[s];
        wt[e][f4*4+0] = v.x; wt[e][f4*4+1] = v.y;
        wt[e][f4*4+2] = v.z; wt[e][f4*4+3] = v.w;
    }
    __syncthreads();
    #pragma unroll
    for (int j = 0; j < 2; ++j) {
        int s = tid + j*256;             // 16B slot 0..511
        int f = s >> 3, e8 = s & 7;
        s16x8 o;
        #pragma unroll
        for (int q = 0; q < 8; ++q) o[q] = (short)f2bf(wt[e8*8+q][f]);
        *(s16x8*)(WbT + ((long)(g*64+f))*512 + h*64 + e8*8) = o;
    }
}

// ---------------------------------------------------------------------------
// K4c: FFN GEMM via MFMA + fused residual/gelu/LN2 epilogue.
//   C[64 tok][64 f] = Z[64 tok][512k] x W[512k][g-block 64]   (bf16 MFMA)
//   out = LN2(gelu(zn + C)).  Block = (bm, g); BN=64 == LN2 granularity.
//   LDS XOR-swizzle (slot ^= row&7) for conflict-free b128 fragment reads.
// ---------------------------------------------------------------------------
__global__ __launch_bounds__(256) void ffn_gemm_kernel(
    const unsigned short* __restrict__ Zb,   // [4096][512] bf16
    const unsigned short* __restrict__ WbT,  // [512 n][512 k] bf16
    const float* __restrict__ g2, const float* __restrict__ b2,
    float* __restrict__ out)                 // [B,G,T,F]
{
    int bm = blockIdx.x >> 3;            // 0..63 token block
    int g  = blockIdx.x & 7;             // output head block
    int m0 = bm*64;
    int tid = threadIdx.x;
    int w = tid >> 6, l = tid & 63;
    int lg = l >> 4, r = l & 15;
    int wr = w >> 1, wc = w & 1;

    __shared__ __align__(16) unsigned short As[4096];  // [64 m][64 k] swz, 8 KB
    __shared__ __align__(16) unsigned short Bs[4096];  // [64 n][64 k] swz, 8 KB
    __shared__ float yL[64][68];                       // C tile, 17.4 KB

    f32x4 acc[2][2] = {{{0.f,0.f,0.f,0.f},{0.f,0.f,0.f,0.f}},
                       {{0.f,0.f,0.f,0.f},{0.f,0.f,0.f,0.f}}};

    for (int kc = 0; kc < 8; ++kc) {
        #pragma unroll
        for (int j = 0; j < 2; ++j) {
            int s = tid + j*256;         // 16B slot 0..511
            int row = s >> 3, c16 = s & 7;
            s16x8 va = *(const s16x8*)(Zb  + ((long)(m0 + row))*512   + kc*64 + c16*8);
            s16x8 vb = *(const s16x8*)(WbT + ((long)(g*64 + row))*512 + kc*64 + c16*8);
            *(s16x8*)&As[row*64 + ((c16 ^ (row & 7))*8)] = va;
            *(s16x8*)&Bs[row*64 + ((c16 ^ (row & 7))*8)] = vb;
        }
        __syncthreads();
        #pragma unroll
        for (int kk = 0; kk < 2; ++kk) {
            s16x8 af[2], bf[2];
            #pragma unroll
            for (int mi = 0; mi < 2; ++mi) {
                int row = wr*32 + mi*16 + r;
                af[mi] = *(const s16x8*)&As[row*64 + (((kk*4 + lg) ^ (row & 7))*8)];
            }
            #pragma unroll
            for (int ni = 0; ni < 2; ++ni) {
                int row = wc*32 + ni*16 + r;
                bf[ni] = *(const s16x8*)&Bs[row*64 + (((kk*4 + lg) ^ (row & 7))*8)];
            }
            #pragma unroll
            for (int mi = 0; mi < 2; ++mi)
                #pragma unroll
                for (int ni = 0; ni < 2; ++ni)
                    acc[mi][ni] = __builtin_amdgcn_mfma_f32_16x16x32_bf16(
                        af[mi], bf[ni], acc[mi][ni], 0, 0, 0);
        }
        __syncthreads();
    }

    // scatter C to yL (C layout: col=lane&15, row=(lane>>4)*4+i)
    #pragma unroll
    for (int mi = 0; mi < 2; ++mi)
        #pragma unroll
        for (int ni = 0; ni < 2; ++ni)
            #pragma unroll
            for (int i = 0; i < 4; ++i)
                yL[wr*32 + mi*16 + lg*4 + i][wc*32 + ni*16 + r] = acc[mi][ni][i];
    __syncthreads();

    // residual + gelu + LN2: quad of lanes per token row (4 x 16 elems)
    int rowt = tid >> 2, part = tid & 3;
    const unsigned short* zrow = Zb + ((long)(m0 + rowt))*512 + g*64 + part*16;
    s16x8 z0 = *(const s16x8*)zrow;
    s16x8 z1 = *(const s16x8*)(zrow + 8);
    const float kg = 0.7978845608028654f;
    float y[16];
    float s = 0.f, s2 = 0.f;
    #pragma unroll
    for (int q = 0; q < 16; ++q) {
        float zn = bf2f((unsigned short)(q < 8 ? z0[q] : z1[q-8]));
        float x = zn + yL[rowt][part*16 + q];
        x = 0.5f*x*(1.f + tanhf(kg*(x + 0.044715f*x*x*x)));
        y[q] = x; s += x; s2 += x*x;
    }
    s  += __shfl_xor(s,  1, 64);  s  += __shfl_xor(s,  2, 64);
    s2 += __shfl_xor(s2, 1, 64);  s2 += __shfl_xor(s2, 2, 64);
    float mu  = s * (1.f/64.f);
    float var = s2 * (1.f/64.f) - mu*mu;
    float rs  = rsqrtf(var + 1e-3f);

    int token = m0 + rowt;
    int b = token >> 11, t = token & 2047;
    long ob = (((long)(b*H + g))*T + t)*64 + part*16;
    #pragma unroll
    for (int q = 0; q < 16; ++q) {
        int f = part*16 + q;
        y[q] = g2[f]*(y[q] - mu)*rs + b2[f];
    }
    #pragma unroll
    for (int q = 0; q < 4; ++q) {
        float4 o = { y[q*4], y[q*4+1], y[q*4+2], y[q*4+3] };
        *(float4*)(out + ob + q*4) = o;
    }
}

// ---------------------------------------------------------------------------
extern "C" void kernel_launch(void* const* d_in, const int* in_sizes, int n_in,
                              void* d_out, int out_size, void* d_ws, size_t ws_size,
                              hipStream_t stream) {
    const float* emb  = (const float*)d_in[0];
    const float* keyk = (const float*)d_in[1];
    const float* qryk = (const float*)d_in[2];
    const float* valk = (const float*)d_in[3];
    const float* ffk  = (const float*)d_in[4];
    const float* g1   = (const float*)d_in[5];
    const float* b1   = (const float*)d_in[6];
    const float* g2   = (const float*)d_in[7];
    const float* b2   = (const float*)d_in[8];
    float* out = (float*)d_out;

    float* ws   = (float*)d_ws;
    float* qs   = ws;                         // 32768 floats
    float* ks   = ws + 32768;                 // 32768
    float* kmx  = ws + 65536;                 // 16
    float* kmn  = ws + 65552;                 // 16
    unsigned short* vT = (unsigned short*)(ws + 65568);    // 2,097,152 bf16 (1,048,576 float slots)
    float* zpre = ws + 65568 + 1048576;       // 2,097,152 floats
    // Zb OVERLAYS vT: vT is dead after attn_kernel; stream order makes this
    // deterministic (qkvT writes vT -> attn reads vT -> ln1 overwrites as Zb).
    unsigned short* Zb  = vT;                               // 2,097,152 bf16
    unsigned short* WbT = (unsigned short*)(ws + 65568 + 1048576 + 2097152); // 262,144 bf16

    qkvT_kernel<<<B*T/16, 256, 0, stream>>>(emb, qryk, keyk, valk, qs, ks, vT);
    minmax_kernel<<<B*H, 256, 0, stream>>>(ks, kmx, kmn);
    attn_kernel<<<B*H*(T/32), 256, 0, stream>>>(qs, ks, kmx, kmn, vT, emb, zpre);
    ln1_kernel<<<B*H*T/4, 256, 0, stream>>>(zpre, g1, b1, Zb);
    wcvt_kernel<<<H*H, 256, 0, stream>>>(ffk, WbT);
    ffn_gemm_kernel<<<(B*T/64)*H, 256, 0, stream>>>(Zb, WbT, g2, b2, out);
}

// Round 9
// 112.349 us; speedup vs baseline: 3.4210x; 1.0052x over previous
//
#include <hip/hip_runtime.h>
#include <math.h>

#define T 2048
#define E 64
#define H 8
#define B 2

typedef __attribute__((ext_vector_type(4))) float f32x4;
typedef __attribute__((ext_vector_type(8))) short s16x8;

static __device__ __forceinline__ unsigned short f2bf(float x) {
    union { float f; unsigned u; } v; v.f = x;
    unsigned r = v.u + 0x7FFFu + ((v.u >> 16) & 1u);   // RNE
    return (unsigned short)(r >> 16);
}
static __device__ __forceinline__ float bf2f(unsigned short u) {
    union { unsigned u; float f; } v; v.u = ((unsigned)u) << 16;
    return v.f;
}

// ---------------------------------------------------------------------------
// K1: per-token projections. qs/ks fp32 [bh][t]; V written TRANSPOSED bf16:
//     vT[bh][f][t]  so attention can stage V^T rows (k-contiguous) coalesced.
// ---------------------------------------------------------------------------
__global__ __launch_bounds__(256) void qkvT_kernel(
    const float* __restrict__ emb,   // [B,T,E]
    const float* __restrict__ qk,    // [H,E]
    const float* __restrict__ kk,    // [H,E]
    const float* __restrict__ vk,    // [H,E,E]
    float* __restrict__ qs,          // [B*H,T]
    float* __restrict__ ks,          // [B*H,T]
    unsigned short* __restrict__ vT) // [B*H,E(f),T] bf16
{
    int b  = blockIdx.x >> 7;
    int t0 = (blockIdx.x & 127) * 16;
    int tid = threadIdx.x;

    __shared__ __align__(16) float eL[16][64];   // 4 KB
    __shared__ __align__(16) float wL[1024];     // qk | kk, 4 KB

    ((float4*)eL)[tid] = ((const float4*)(emb + ((long)b*T + t0)*E))[tid];
    ((float4*)wL)[tid & 255] = (tid < 128) ? ((const float4*)qk)[tid]
                                           : ((const float4*)kk)[tid - 128];
    __syncthreads();

    // ---- scores: 16 tokens x (8 q + 8 k) dots of length 64
    {
        int tl = tid >> 4, sc = tid & 15;
        int h = sc & 7, sel = sc >> 3;           // sel=0 -> q, 1 -> k
        const float* wp = wL + sel*512 + h*64;
        float s = 0.f;
        #pragma unroll
        for (int e = 0; e < 64; ++e) {
            int ei = (e + sc*4) & 63;            // stagger banks
            s += eL[tl][ei] * wp[ei];
        }
        float* dst = sel ? ks : qs;
        dst[((long)b*H + h)*T + t0 + tl] = s;
    }

    // ---- V projection: thread -> 2 (h,f) pairs, 16 tokens each
    #pragma unroll
    for (int p = 0; p < 2; ++p) {
        int hf = tid + p*256;
        int h = hf >> 6, f = hf & 63;
        float acc[16];
        #pragma unroll
        for (int t = 0; t < 16; ++t) acc[t] = 0.f;
        #pragma unroll 4
        for (int e = 0; e < 64; ++e) {
            float w = vk[(h*64 + e)*64 + f];     // coalesced across lanes
            #pragma unroll
            for (int t = 0; t < 16; ++t) acc[t] += eL[t][e] * w;  // LDS broadcast
        }
        long row = ((long)(b*H + h)*64 + f) * (long)T;
        s16x8 o0, o1;
        #pragma unroll
        for (int t = 0; t < 8; ++t) { o0[t] = (short)f2bf(acc[t]); o1[t] = (short)f2bf(acc[t+8]); }
        *(s16x8*)(vT + row + t0)     = o0;
        *(s16x8*)(vT + row + t0 + 8) = o1;
    }
}

// ---------------------------------------------------------------------------
// K2: per-(b,h) min/max of ks (exact softmax max for rank-1 scores)
// ---------------------------------------------------------------------------
__global__ __launch_bounds__(256) void minmax_kernel(
    const float* __restrict__ ks, float* __restrict__ kmax, float* __restrict__ kmin)
{
    int bh = blockIdx.x;
    int tid = threadIdx.x;
    float mx = -1e30f, mn = 1e30f;
    for (int i = tid; i < T; i += 256) {
        float x = ks[(long)bh*T + i];
        mx = fmaxf(mx, x); mn = fminf(mn, x);
    }
    __shared__ float smx[256], smn[256];
    smx[tid] = mx; smn[tid] = mn;
    __syncthreads();
    for (int s = 128; s > 0; s >>= 1) {
        if (tid < s) {
            smx[tid] = fmaxf(smx[tid], smx[tid+s]);
            smn[tid] = fminf(smn[tid], smn[tid+s]);
        }
        __syncthreads();
    }
    if (tid == 0) { kmax[bh] = smx[0]; kmin[bh] = smn[0]; }
}

// ---------------------------------------------------------------------------
// K3: attention via MFMA.  BISECTION CHANGE (a) ONLY vs round-6 measured:
//   Block = (bh, 64 q-rows); wave w owns rows w*16..w*16+15 x ALL 64 f-cols
//   (4 accumulators) -> P (exp+pack) computed ONCE per (row,k), serves 4
//   MFMAs (was 2x duplicated).  f2bf packing (NO inline asm), epilogue
//   writes zpre fp32 (NO LN1 fusion) — both kept identical to round 6.
// ---------------------------------------------------------------------------
__global__ __launch_bounds__(256) void attn_kernel(
    const float* __restrict__ qs, const float* __restrict__ ksg,
    const float* __restrict__ kmax, const float* __restrict__ kmin,
    const unsigned short* __restrict__ vT, const float* __restrict__ emb,
    float* __restrict__ zpre)
{
    int bh = blockIdx.x >> 5;            // 0..15
    int q0 = (blockIdx.x & 31) * 64;
    int b  = bh >> 3;
    int tid = threadIdx.x;
    int w = tid >> 6, l = tid & 63;
    int g = l >> 4, r = l & 15;

    __shared__ __align__(16) float ksL[2048];           // 8 KB
    __shared__ __align__(16) unsigned short VtL[8192];  // [64 f][128 k] bf16, swizzled, 16 KB

    ((float4*)ksL)[tid]       = ((const float4*)(ksg + (long)bh*T))[tid];
    ((float4*)ksL)[tid + 256] = ((const float4*)(ksg + (long)bh*T))[tid + 256];

    float sreg, mreg;
    {
        float s = qs[(long)bh*T + q0 + w*16 + r];
        sreg = s;
        mreg = (s >= 0.f) ? s*kmax[bh] : s*kmin[bh];
    }
    __syncthreads();                     // ksL visible to all waves

    f32x4 acc[4] = {{0.f,0.f,0.f,0.f},{0.f,0.f,0.f,0.f},
                    {0.f,0.f,0.f,0.f},{0.f,0.f,0.f,0.f}};
    float dsum = 0.f;

    for (int kc = 0; kc < 16; ++kc) {
        // stage V^T chunk [64 f][128 k] bf16, 16B-slot swizzle: slot ^= f&15
        #pragma unroll
        for (int j = 0; j < 4; ++j) {
            int i = tid + j*256;         // 16B-slot 0..1023
            int f = i >> 4, s16 = i & 15;
            s16x8 val = *(const s16x8*)(vT + ((long)(bh*64 + f))*T + kc*128 + s16*8);
            *(s16x8*)&VtL[f*128 + ((s16 ^ (f & 15)) * 8)] = val;
        }
        __syncthreads();                 // staging visible
        #pragma unroll
        for (int kw = 0; kw < 4; ++kw) { // 32-k MFMA windows
            int kbase = kc*128 + kw*32 + g*8;
            float4 ka = *(const float4*)&ksL[kbase];
            float4 kb = *(const float4*)&ksL[kbase + 4];
            float p0 = __expf(fmaf(sreg, ka.x, -mreg));
            float p1 = __expf(fmaf(sreg, ka.y, -mreg));
            float p2 = __expf(fmaf(sreg, ka.z, -mreg));
            float p3 = __expf(fmaf(sreg, ka.w, -mreg));
            float p4 = __expf(fmaf(sreg, kb.x, -mreg));
            float p5 = __expf(fmaf(sreg, kb.y, -mreg));
            float p6 = __expf(fmaf(sreg, kb.z, -mreg));
            float p7 = __expf(fmaf(sreg, kb.w, -mreg));
            dsum += ((p0+p1)+(p2+p3)) + ((p4+p5)+(p6+p7));
            s16x8 af;
            af[0] = (short)f2bf(p0); af[1] = (short)f2bf(p1);
            af[2] = (short)f2bf(p2); af[3] = (short)f2bf(p3);
            af[4] = (short)f2bf(p4); af[5] = (short)f2bf(p5);
            af[6] = (short)f2bf(p6); af[7] = (short)f2bf(p7);
            int slot = kw*4 + g;
            #pragma unroll
            for (int ct = 0; ct < 4; ++ct) {
                s16x8 bf = *(const s16x8*)&VtL[(ct*16 + r)*128 + ((slot ^ r) * 8)];
                acc[ct] = __builtin_amdgcn_mfma_f32_16x16x32_bf16(af, bf, acc[ct], 0, 0, 0);
            }
        }
        __syncthreads();                 // compute done before next staging
    }

    // full row-denominator into every lane (per its A-row r)
    dsum += __shfl_xor(dsum, 16, 64);
    dsum += __shfl_xor(dsum, 32, 64);

    #pragma unroll
    for (int i = 0; i < 4; ++i) {
        int lrow = g*4 + i;               // C layout: local row=(lane>>4)*4+i
        float den = __shfl(dsum, lrow, 16);  // lane 16*g+lrow holds row lrow's den
        float inv = 1.f / den;
        long q = q0 + w*16 + lrow;
        const float* erow = emb + ((long)b*T + q)*E;
        #pragma unroll
        for (int ct = 0; ct < 4; ++ct) {
            int f = ct*16 + r;
            zpre[((long)bh*T + q)*E + f] = erow[f] + acc[ct][i] * inv;
        }
    }
}

// ---------------------------------------------------------------------------
// K4a: LN1 over zpre rows of 64, output Z bf16 in GEMM layout:
//      Zb[token = b*T+t][h*64+e].  Wave per row, shfl butterfly reduce.
// ---------------------------------------------------------------------------
__global__ __launch_bounds__(256) void ln1_kernel(
    const float* __restrict__ zpre,  // [B*H,T,64]
    const float* __restrict__ g1, const float* __restrict__ b1,
    unsigned short* __restrict__ Zb) // [B*T,512] bf16
{
    int row  = blockIdx.x*4 + (threadIdx.x >> 6);  // bh*T + t, 0..32767
    int lane = threadIdx.x & 63;
    float x = zpre[(long)row*64 + lane];
    float s = x, s2 = x*x;
    #pragma unroll
    for (int o = 1; o < 64; o <<= 1) {
        s  += __shfl_xor(s,  o, 64);
        s2 += __shfl_xor(s2, o, 64);
    }
    float mu  = s * (1.f/64.f);
    float var = s2 * (1.f/64.f) - mu*mu;
    float rs  = rsqrtf(var + 1e-3f);
    float zn  = g1[lane]*(x - mu)*rs + b1[lane];
    int b = row >> 14, h = (row >> 11) & 7, t = row & 2047;
    long token = (long)b*T + t;
    Zb[token*512 + h*64 + lane] = f2bf(zn);
}

// ---------------------------------------------------------------------------
// K4b: weight transpose+cast: fk[h,g,e,f] fp32 -> WbT[n=g*64+f][k=h*64+e] bf16
// ---------------------------------------------------------------------------
__global__ __launch_bounds__(256) void wcvt_kernel(
    const float* __restrict__ fk, unsigned short* __restrict__ WbT)
{
    int hg = blockIdx.x;                 // h*8+g
    int h = hg >> 3, g = hg & 7;
    int tid = threadIdx.x;
    __shared__ float wt[64][65];         // padded, 16.6 KB
    const float* src = fk + (long)hg*4096;
    #pragma unroll
    for (int j = 0; j < 4; ++j) {
        int s = tid + j*256;             // float4 slot 0..1023
        int e = s >> 4, f4 = s & 15;
        float4 v = ((const float4*)src)[s];
        wt[e][f4*4+0] = v.x; wt[e][f4*4+1] = v.y;
        wt[e][f4*4+2] = v.z; wt[e][f4*4+3] = v.w;
    }
    __syncthreads();
    #pragma unroll
    for (int j = 0; j < 2; ++j) {
        int s = tid + j*256;             // 16B slot 0..511
        int f = s >> 3, e8 = s & 7;
        s16x8 o;
        #pragma unroll
        for (int q = 0; q < 8; ++q) o[q] = (short)f2bf(wt[e8*8+q][f]);
        *(s16x8*)(WbT + ((long)(g*64+f))*512 + h*64 + e8*8) = o;
    }
}

// ---------------------------------------------------------------------------
// K4c: FFN GEMM via MFMA + fused residual/gelu/LN2 epilogue.
//   C[64 tok][64 f] = Z[64 tok][512k] x W[512k][g-block 64]   (bf16 MFMA)
//   out = LN2(gelu(zn + C)).  Block = (bm, g); BN=64 == LN2 granularity.
//   LDS XOR-swizzle (slot ^= row&7) for conflict-free b128 fragment reads.
// ---------------------------------------------------------------------------
__global__ __launch_bounds__(256) void ffn_gemm_kernel(
    const unsigned short* __restrict__ Zb,   // [4096][512] bf16
    const unsigned short* __restrict__ WbT,  // [512 n][512 k] bf16
    const float* __restrict__ g2, const float* __restrict__ b2,
    float* __restrict__ out)                 // [B,G,T,F]
{
    int bm = blockIdx.x >> 3;            // 0..63 token block
    int g  = blockIdx.x & 7;             // output head block
    int m0 = bm*64;
    int tid = threadIdx.x;
    int w = tid >> 6, l = tid & 63;
    int lg = l >> 4, r = l & 15;
    int wr = w >> 1, wc = w & 1;

    __shared__ __align__(16) unsigned short As[4096];  // [64 m][64 k] swz, 8 KB
    __shared__ __align__(16) unsigned short Bs[4096];  // [64 n][64 k] swz, 8 KB
    __shared__ float yL[64][68];                       // C tile, 17.4 KB

    f32x4 acc[2][2] = {{{0.f,0.f,0.f,0.f},{0.f,0.f,0.f,0.f}},
                       {{0.f,0.f,0.f,0.f},{0.f,0.f,0.f,0.f}}};

    for (int kc = 0; kc < 8; ++kc) {
        #pragma unroll
        for (int j = 0; j < 2; ++j) {
            int s = tid + j*256;         // 16B slot 0..511
            int row = s >> 3, c16 = s & 7;
            s16x8 va = *(const s16x8*)(Zb  + ((long)(m0 + row))*512   + kc*64 + c16*8);
            s16x8 vb = *(const s16x8*)(WbT + ((long)(g*64 + row))*512 + kc*64 + c16*8);
            *(s16x8*)&As[row*64 + ((c16 ^ (row & 7))*8)] = va;
            *(s16x8*)&Bs[row*64 + ((c16 ^ (row & 7))*8)] = vb;
        }
        __syncthreads();
        #pragma unroll
        for (int kk = 0; kk < 2; ++kk) {
            s16x8 af[2], bf[2];
            #pragma unroll
            for (int mi = 0; mi < 2; ++mi) {
                int row = wr*32 + mi*16 + r;
                af[mi] = *(const s16x8*)&As[row*64 + (((kk*4 + lg) ^ (row & 7))*8)];
            }
            #pragma unroll
            for (int ni = 0; ni < 2; ++ni) {
                int row = wc*32 + ni*16 + r;
                bf[ni] = *(const s16x8*)&Bs[row*64 + (((kk*4 + lg) ^ (row & 7))*8)];
            }
            #pragma unroll
            for (int mi = 0; mi < 2; ++mi)
                #pragma unroll
                for (int ni = 0; ni < 2; ++ni)
                    acc[mi][ni] = __builtin_amdgcn_mfma_f32_16x16x32_bf16(
                        af[mi], bf[ni], acc[mi][ni], 0, 0, 0);
        }
        __syncthreads();
    }

    // scatter C to yL (C layout: col=lane&15, row=(lane>>4)*4+i)
    #pragma unroll
    for (int mi = 0; mi < 2; ++mi)
        #pragma unroll
        for (int ni = 0; ni < 2; ++ni)
            #pragma unroll
            for (int i = 0; i < 4; ++i)
                yL[wr*32 + mi*16 + lg*4 + i][wc*32 + ni*16 + r] = acc[mi][ni][i];
    __syncthreads();

    // residual + gelu + LN2: quad of lanes per token row (4 x 16 elems)
    int rowt = tid >> 2, part = tid & 3;
    const unsigned short* zrow = Zb + ((long)(m0 + rowt))*512 + g*64 + part*16;
    s16x8 z0 = *(const s16x8*)zrow;
    s16x8 z1 = *(const s16x8*)(zrow + 8);
    const float kg = 0.7978845608028654f;
    float y[16];
    float s = 0.f, s2 = 0.f;
    #pragma unroll
    for (int q = 0; q < 16; ++q) {
        float zn = bf2f((unsigned short)(q < 8 ? z0[q] : z1[q-8]));
        float x = zn + yL[rowt][part*16 + q];
        x = 0.5f*x*(1.f + tanhf(kg*(x + 0.044715f*x*x*x)));
        y[q] = x; s += x; s2 += x*x;
    }
    s  += __shfl_xor(s,  1, 64);  s  += __shfl_xor(s,  2, 64);
    s2 += __shfl_xor(s2, 1, 64);  s2 += __shfl_xor(s2, 2, 64);
    float mu  = s * (1.f/64.f);
    float var = s2 * (1.f/64.f) - mu*mu;
    float rs  = rsqrtf(var + 1e-3f);

    int token = m0 + rowt;
    int b = token >> 11, t = token & 2047;
    long ob = (((long)(b*H + g))*T + t)*64 + part*16;
    #pragma unroll
    for (int q = 0; q < 16; ++q) {
        int f = part*16 + q;
        y[q] = g2[f]*(y[q] - mu)*rs + b2[f];
    }
    #pragma unroll
    for (int q = 0; q < 4; ++q) {
        float4 o = { y[q*4], y[q*4+1], y[q*4+2], y[q*4+3] };
        *(float4*)(out + ob + q*4) = o;
    }
}

// ---------------------------------------------------------------------------
extern "C" void kernel_launch(void* const* d_in, const int* in_sizes, int n_in,
                              void* d_out, int out_size, void* d_ws, size_t ws_size,
                              hipStream_t stream) {
    const float* emb  = (const float*)d_in[0];
    const float* keyk = (const float*)d_in[1];
    const float* qryk = (const float*)d_in[2];
    const float* valk = (const float*)d_in[3];
    const float* ffk  = (const float*)d_in[4];
    const float* g1   = (const float*)d_in[5];
    const float* b1   = (const float*)d_in[6];
    const float* g2   = (const float*)d_in[7];
    const float* b2   = (const float*)d_in[8];
    float* out = (float*)d_out;

    float* ws   = (float*)d_ws;
    float* qs   = ws;                         // 32768 floats
    float* ks   = ws + 32768;                 // 32768
    float* kmx  = ws + 65536;                 // 16
    float* kmn  = ws + 65552;                 // 16
    unsigned short* vT = (unsigned short*)(ws + 65568);   // 2,097,152 bf16
    float* zpre = ws + 65568 + 1048576;       // 2,097,152 floats
    // Zb OVERLAYS vT: vT is dead after attn_kernel; stream order makes this
    // deterministic (qkvT writes vT -> attn reads vT -> ln1 overwrites as Zb).
    unsigned short* Zb  = vT;                               // 2,097,152 bf16
    unsigned short* WbT = (unsigned short*)(ws + 65568 + 1048576 + 2097152); // 262,144 bf16

    qkvT_kernel<<<B*T/16, 256, 0, stream>>>(emb, qryk, keyk, valk, qs, ks, vT);
    minmax_kernel<<<B*H, 256, 0, stream>>>(ks, kmx, kmn);
    attn_kernel<<<B*H*(T/64), 256, 0, stream>>>(qs, ks, kmx, kmn, vT, emb, zpre);
    ln1_kernel<<<B*H*T/4, 256, 0, stream>>>(zpre, g1, b1, Zb);
    wcvt_kernel<<<H*H, 256, 0, stream>>>(ffk, WbT);
    ffn_gemm_kernel<<<(B*T/64)*H, 256, 0, stream>>>(Zb, WbT, g2, b2, out);
}

// Round 10
// 100.457 us; speedup vs baseline: 3.8259x; 1.1184x over previous
//
#include <hip/hip_runtime.h>
#include <math.h>

#define T 2048
#define E 64
#define H 8
#define B 2

typedef __attribute__((ext_vector_type(4))) float f32x4;
typedef __attribute__((ext_vector_type(8))) short s16x8;
typedef __attribute__((ext_vector_type(4))) short s16x4;

static __device__ __forceinline__ unsigned short f2bf(float x) {
    union { float f; unsigned u; } v; v.f = x;
    unsigned r = v.u + 0x7FFFu + ((v.u >> 16) & 1u);   // RNE
    return (unsigned short)(r >> 16);
}
static __device__ __forceinline__ float bf2f(unsigned short u) {
    union { unsigned u; float f; } v; v.u = ((unsigned)u) << 16;
    return v.f;
}

// ---------------------------------------------------------------------------
// K1: per-token projections. 4 tokens/block -> 1024 blocks (16 waves/CU) so
//     vk load latency is TLP-hidden (was 256 blocks, 9.9% occupancy).
// ---------------------------------------------------------------------------
__global__ __launch_bounds__(256) void qkvT_kernel(
    const float* __restrict__ emb,   // [B,T,E]
    const float* __restrict__ qk,    // [H,E]
    const float* __restrict__ kk,    // [H,E]
    const float* __restrict__ vk,    // [H,E,E]
    float* __restrict__ qs,          // [B*H,T]
    float* __restrict__ ks,          // [B*H,T]
    unsigned short* __restrict__ vT) // [B*H,E(f),T] bf16
{
    int b  = blockIdx.x >> 9;            // 1024 blocks
    int t0 = (blockIdx.x & 511) * 4;
    int tid = threadIdx.x;

    __shared__ __align__(16) float eL[4][64];    // 1 KB
    __shared__ __align__(16) float wL[1024];     // qk | kk, 4 KB

    if (tid < 64) ((float4*)eL)[tid] = ((const float4*)(emb + ((long)b*T + t0)*E))[tid];
    ((float4*)wL)[tid] = (tid < 128) ? ((const float4*)qk)[tid]
                                     : ((const float4*)kk)[tid - 128];
    __syncthreads();

    // ---- scores: 4 tokens x (8 q + 8 k) dots of length 64
    if (tid < 64) {
        int tl = tid >> 4, sc = tid & 15;
        int h = sc & 7, sel = sc >> 3;           // sel=0 -> q, 1 -> k
        const float* wp = wL + sel*512 + h*64;
        float s = 0.f;
        #pragma unroll
        for (int e = 0; e < 64; ++e) {
            int ei = (e + sc*4) & 63;            // stagger banks
            s += eL[tl][ei] * wp[ei];
        }
        float* dst = sel ? ks : qs;
        dst[((long)b*H + h)*T + t0 + tl] = s;
    }

    // ---- V projection: thread -> 2 (h,f) pairs, 4 tokens each
    #pragma unroll
    for (int p = 0; p < 2; ++p) {
        int hf = tid + p*256;
        int h = hf >> 6, f = hf & 63;
        float a0 = 0.f, a1 = 0.f, a2 = 0.f, a3 = 0.f;
        #pragma unroll 8
        for (int e = 0; e < 64; ++e) {
            float w = vk[(h*64 + e)*64 + f];     // coalesced across lanes
            a0 += eL[0][e]*w; a1 += eL[1][e]*w;
            a2 += eL[2][e]*w; a3 += eL[3][e]*w;
        }
        long row = ((long)(b*H + h)*64 + f) * (long)T;
        s16x4 o;
        o[0] = (short)f2bf(a0); o[1] = (short)f2bf(a1);
        o[2] = (short)f2bf(a2); o[3] = (short)f2bf(a3);
        *(s16x4*)(vT + row + t0) = o;
    }
}

// ---------------------------------------------------------------------------
// K2: per-(b,h) min/max of ks (exact softmax max for rank-1 scores)
// ---------------------------------------------------------------------------
__global__ __launch_bounds__(256) void minmax_kernel(
    const float* __restrict__ ks, float* __restrict__ kmax, float* __restrict__ kmin)
{
    int bh = blockIdx.x;
    int tid = threadIdx.x;
    float mx = -1e30f, mn = 1e30f;
    for (int i = tid; i < T; i += 256) {
        float x = ks[(long)bh*T + i];
        mx = fmaxf(mx, x); mn = fminf(mn, x);
    }
    __shared__ float smx[256], smn[256];
    smx[tid] = mx; smn[tid] = mn;
    __syncthreads();
    for (int s = 128; s > 0; s >>= 1) {
        if (tid < s) {
            smx[tid] = fmaxf(smx[tid], smx[tid+s]);
            smn[tid] = fminf(smn[tid], smn[tid+s]);
        }
        __syncthreads();
    }
    if (tid == 0) { kmax[bh] = smx[0]; kmin[bh] = smn[0]; }
}

// ---------------------------------------------------------------------------
// K3: attention via MFMA, double-buffered V staging (T14 async-STAGE):
//   per kc: issue global loads for kc+1 -> compute kc from VtL[cur] ->
//   write prefetch regs to VtL[cur^1] -> ONE barrier.  Load latency hides
//   under the 16-MFMA compute phase; 16 barriers instead of 32.
// ---------------------------------------------------------------------------
__global__ __launch_bounds__(256) void attn_kernel(
    const float* __restrict__ qs, const float* __restrict__ ksg,
    const float* __restrict__ kmax, const float* __restrict__ kmin,
    const unsigned short* __restrict__ vT, const float* __restrict__ emb,
    float* __restrict__ zpre)
{
    int bh = blockIdx.x >> 5;            // 0..15
    int q0 = (blockIdx.x & 31) * 64;
    int b  = bh >> 3;
    int tid = threadIdx.x;
    int w = tid >> 6, l = tid & 63;
    int g = l >> 4, r = l & 15;

    __shared__ __align__(16) float ksL[2048];              // 8 KB
    __shared__ __align__(16) unsigned short VtL[2][8192];  // 2x[64 f][128 k] swz, 32 KB

    ((float4*)ksL)[tid]       = ((const float4*)(ksg + (long)bh*T))[tid];
    ((float4*)ksL)[tid + 256] = ((const float4*)(ksg + (long)bh*T))[tid + 256];

    float sreg, mreg;
    {
        float s = qs[(long)bh*T + q0 + w*16 + r];
        sreg = s;
        mreg = (s >= 0.f) ? s*kmax[bh] : s*kmin[bh];
    }

    // prologue: stage chunk 0 into VtL[0]
    #pragma unroll
    for (int j = 0; j < 4; ++j) {
        int i = tid + j*256;             // 16B-slot 0..1023
        int f = i >> 4, si = i & 15;
        s16x8 val = *(const s16x8*)(vT + ((long)(bh*64 + f))*T + si*8);
        *(s16x8*)&VtL[0][f*128 + ((si ^ (f & 15)) * 8)] = val;
    }
    __syncthreads();                     // ksL + chunk0 visible

    f32x4 acc[4] = {{0.f,0.f,0.f,0.f},{0.f,0.f,0.f,0.f},
                    {0.f,0.f,0.f,0.f},{0.f,0.f,0.f,0.f}};
    float dsum = 0.f;

    for (int kc = 0; kc < 16; ++kc) {
        int cur = kc & 1;
        // issue prefetch loads for next chunk (latency hides under compute)
        s16x8 pf[4];
        if (kc < 15) {
            #pragma unroll
            for (int j = 0; j < 4; ++j) {
                int i = tid + j*256;
                int f = i >> 4, si = i & 15;
                pf[j] = *(const s16x8*)(vT + ((long)(bh*64 + f))*T + (kc+1)*128 + si*8);
            }
        }
        // compute chunk kc from VtL[cur]
        #pragma unroll
        for (int kw = 0; kw < 4; ++kw) { // 32-k MFMA windows
            int kbase = kc*128 + kw*32 + g*8;
            float4 ka = *(const float4*)&ksL[kbase];
            float4 kb = *(const float4*)&ksL[kbase + 4];
            float p0 = __expf(fmaf(sreg, ka.x, -mreg));
            float p1 = __expf(fmaf(sreg, ka.y, -mreg));
            float p2 = __expf(fmaf(sreg, ka.z, -mreg));
            float p3 = __expf(fmaf(sreg, ka.w, -mreg));
            float p4 = __expf(fmaf(sreg, kb.x, -mreg));
            float p5 = __expf(fmaf(sreg, kb.y, -mreg));
            float p6 = __expf(fmaf(sreg, kb.z, -mreg));
            float p7 = __expf(fmaf(sreg, kb.w, -mreg));
            dsum += ((p0+p1)+(p2+p3)) + ((p4+p5)+(p6+p7));
            s16x8 af;
            af[0] = (short)f2bf(p0); af[1] = (short)f2bf(p1);
            af[2] = (short)f2bf(p2); af[3] = (short)f2bf(p3);
            af[4] = (short)f2bf(p4); af[5] = (short)f2bf(p5);
            af[6] = (short)f2bf(p6); af[7] = (short)f2bf(p7);
            int slot = kw*4 + g;
            #pragma unroll
            for (int ct = 0; ct < 4; ++ct) {
                s16x8 bf = *(const s16x8*)&VtL[cur][(ct*16 + r)*128 + ((slot ^ r) * 8)];
                acc[ct] = __builtin_amdgcn_mfma_f32_16x16x32_bf16(af, bf, acc[ct], 0, 0, 0);
            }
        }
        // write prefetched chunk to the other buffer (no conflict with cur reads)
        if (kc < 15) {
            #pragma unroll
            for (int j = 0; j < 4; ++j) {
                int i = tid + j*256;
                int f = i >> 4, si = i & 15;
                *(s16x8*)&VtL[cur ^ 1][f*128 + ((si ^ (f & 15)) * 8)] = pf[j];
            }
        }
        __syncthreads();                 // next-chunk staging visible
    }

    // full row-denominator into every lane (per its A-row r)
    dsum += __shfl_xor(dsum, 16, 64);
    dsum += __shfl_xor(dsum, 32, 64);

    #pragma unroll
    for (int i = 0; i < 4; ++i) {
        int lrow = g*4 + i;               // C layout: local row=(lane>>4)*4+i
        float den = __shfl(dsum, lrow, 16);  // lane 16*g+lrow holds row lrow's den
        float inv = 1.f / den;
        long q = q0 + w*16 + lrow;
        const float* erow = emb + ((long)b*T + q)*E;
        #pragma unroll
        for (int ct = 0; ct < 4; ++ct) {
            int f = ct*16 + r;
            zpre[((long)bh*T + q)*E + f] = erow[f] + acc[ct][i] * inv;
        }
    }
}

// ---------------------------------------------------------------------------
// K4a: LN1 over zpre rows of 64, output Z bf16 in GEMM layout:
//      Zb[token = b*T+t][h*64+e].  Wave per row, shfl butterfly reduce.
// ---------------------------------------------------------------------------
__global__ __launch_bounds__(256) void ln1_kernel(
    const float* __restrict__ zpre,  // [B*H,T,64]
    const float* __restrict__ g1, const float* __restrict__ b1,
    unsigned short* __restrict__ Zb) // [B*T,512] bf16
{
    int row  = blockIdx.x*4 + (threadIdx.x >> 6);  // bh*T + t, 0..32767
    int lane = threadIdx.x & 63;
    float x = zpre[(long)row*64 + lane];
    float s = x, s2 = x*x;
    #pragma unroll
    for (int o = 1; o < 64; o <<= 1) {
        s  += __shfl_xor(s,  o, 64);
        s2 += __shfl_xor(s2, o, 64);
    }
    float mu  = s * (1.f/64.f);
    float var = s2 * (1.f/64.f) - mu*mu;
    float rs  = rsqrtf(var + 1e-3f);
    float zn  = g1[lane]*(x - mu)*rs + b1[lane];
    int b = row >> 14, h = (row >> 11) & 7, t = row & 2047;
    long token = (long)b*T + t;
    Zb[token*512 + h*64 + lane] = f2bf(zn);
}

// ---------------------------------------------------------------------------
// K4b: weight transpose+cast: fk[h,g,e,f] fp32 -> WbT[n=g*64+f][k=h*64+e] bf16
// ---------------------------------------------------------------------------
__global__ __launch_bounds__(256) void wcvt_kernel(
    const float* __restrict__ fk, unsigned short* __restrict__ WbT)
{
    int hg = blockIdx.x;                 // h*8+g
    int h = hg >> 3, g = hg & 7;
    int tid = threadIdx.x;
    __shared__ float wt[64][65];         // padded, 16.6 KB
    const float* src = fk + (long)hg*4096;
    #pragma unroll
    for (int j = 0; j < 4; ++j) {
        int s = tid + j*256;             // float4 slot 0..1023
        int e = s >> 4, f4 = s & 15;
        float4 v = ((const float4*)src)[s];
        wt[e][f4*4+0] = v.x; wt[e][f4*4+1] = v.y;
        wt[e][f4*4+2] = v.z; wt[e][f4*4+3] = v.w;
    }
    __syncthreads();
    #pragma unroll
    for (int j = 0; j < 2; ++j) {
        int s = tid + j*256;             // 16B slot 0..511
        int f = s >> 3, e8 = s & 7;
        s16x8 o;
        #pragma unroll
        for (int q = 0; q < 8; ++q) o[q] = (short)f2bf(wt[e8*8+q][f]);
        *(s16x8*)(WbT + ((long)(g*64+f))*512 + h*64 + e8*8) = o;
    }
}

// ---------------------------------------------------------------------------
// K4c: FFN GEMM via MFMA + fused residual/gelu/LN2 epilogue.
//   C[64 tok][64 f] = Z[64 tok][512k] x W[512k][g-block 64]   (bf16 MFMA)
//   out = LN2(gelu(zn + C)).  Block = (bm, g); BN=64 == LN2 granularity.
//   LDS XOR-swizzle (slot ^= row&7) for conflict-free b128 fragment reads.
// ---------------------------------------------------------------------------
__global__ __launch_bounds__(256) void ffn_gemm_kernel(
    const unsigned short* __restrict__ Zb,   // [4096][512] bf16
    const unsigned short* __restrict__ WbT,  // [512 n][512 k] bf16
    const float* __restrict__ g2, const float* __restrict__ b2,
    float* __restrict__ out)                 // [B,G,T,F]
{
    int bm = blockIdx.x >> 3;            // 0..63 token block
    int g  = blockIdx.x & 7;             // output head block
    int m0 = bm*64;
    int tid = threadIdx.x;
    int w = tid >> 6, l = tid & 63;
    int lg = l >> 4, r = l & 15;
    int wr = w >> 1, wc = w & 1;

    __shared__ __align__(16) unsigned short As[4096];  // [64 m][64 k] swz, 8 KB
    __shared__ __align__(16) unsigned short Bs[4096];  // [64 n][64 k] swz, 8 KB
    __shared__ float yL[64][68];                       // C tile, 17.4 KB

    f32x4 acc[2][2] = {{{0.f,0.f,0.f,0.f},{0.f,0.f,0.f,0.f}},
                       {{0.f,0.f,0.f,0.f},{0.f,0.f,0.f,0.f}}};

    for (int kc = 0; kc < 8; ++kc) {
        #pragma unroll
        for (int j = 0; j < 2; ++j) {
            int s = tid + j*256;         // 16B slot 0..511
            int row = s >> 3, c16 = s & 7;
            s16x8 va = *(const s16x8*)(Zb  + ((long)(m0 + row))*512   + kc*64 + c16*8);
            s16x8 vb = *(const s16x8*)(WbT + ((long)(g*64 + row))*512 + kc*64 + c16*8);
            *(s16x8*)&As[row*64 + ((c16 ^ (row & 7))*8)] = va;
            *(s16x8*)&Bs[row*64 + ((c16 ^ (row & 7))*8)] = vb;
        }
        __syncthreads();
        #pragma unroll
        for (int kk = 0; kk < 2; ++kk) {
            s16x8 af[2], bf[2];
            #pragma unroll
            for (int mi = 0; mi < 2; ++mi) {
                int row = wr*32 + mi*16 + r;
                af[mi] = *(const s16x8*)&As[row*64 + (((kk*4 + lg) ^ (row & 7))*8)];
            }
            #pragma unroll
            for (int ni = 0; ni < 2; ++ni) {
                int row = wc*32 + ni*16 + r;
                bf[ni] = *(const s16x8*)&Bs[row*64 + (((kk*4 + lg) ^ (row & 7))*8)];
            }
            #pragma unroll
            for (int mi = 0; mi < 2; ++mi)
                #pragma unroll
                for (int ni = 0; ni < 2; ++ni)
                    acc[mi][ni] = __builtin_amdgcn_mfma_f32_16x16x32_bf16(
                        af[mi], bf[ni], acc[mi][ni], 0, 0, 0);
        }
        __syncthreads();
    }

    // scatter C to yL (C layout: col=lane&15, row=(lane>>4)*4+i)
    #pragma unroll
    for (int mi = 0; mi < 2; ++mi)
        #pragma unroll
        for (int ni = 0; ni < 2; ++ni)
            #pragma unroll
            for (int i = 0; i < 4; ++i)
                yL[wr*32 + mi*16 + lg*4 + i][wc*32 + ni*16 + r] = acc[mi][ni][i];
    __syncthreads();

    // residual + gelu + LN2: quad of lanes per token row (4 x 16 elems)
    int rowt = tid >> 2, part = tid & 3;
    const unsigned short* zrow = Zb + ((long)(m0 + rowt))*512 + g*64 + part*16;
    s16x8 z0 = *(const s16x8*)zrow;
    s16x8 z1 = *(const s16x8*)(zrow + 8);
    const float kg = 0.7978845608028654f;
    float y[16];
    float s = 0.f, s2 = 0.f;
    #pragma unroll
    for (int q = 0; q < 16; ++q) {
        float zn = bf2f((unsigned short)(q < 8 ? z0[q] : z1[q-8]));
        float x = zn + yL[rowt][part*16 + q];
        x = 0.5f*x*(1.f + tanhf(kg*(x + 0.044715f*x*x*x)));
        y[q] = x; s += x; s2 += x*x;
    }
    s  += __shfl_xor(s,  1, 64);  s  += __shfl_xor(s,  2, 64);
    s2 += __shfl_xor(s2, 1, 64);  s2 += __shfl_xor(s2, 2, 64);
    float mu  = s * (1.f/64.f);
    float var = s2 * (1.f/64.f) - mu*mu;
    float rs  = rsqrtf(var + 1e-3f);

    int token = m0 + rowt;
    int b = token >> 11, t = token & 2047;
    long ob = (((long)(b*H + g))*T + t)*64 + part*16;
    #pragma unroll
    for (int q = 0; q < 16; ++q) {
        int f = part*16 + q;
        y[q] = g2[f]*(y[q] - mu)*rs + b2[f];
    }
    #pragma unroll
    for (int q = 0; q < 4; ++q) {
        float4 o = { y[q*4], y[q*4+1], y[q*4+2], y[q*4+3] };
        *(float4*)(out + ob + q*4) = o;
    }
}

// ---------------------------------------------------------------------------
extern "C" void kernel_launch(void* const* d_in, const int* in_sizes, int n_in,
                              void* d_out, int out_size, void* d_ws, size_t ws_size,
                              hipStream_t stream) {
    const float* emb  = (const float*)d_in[0];
    const float* keyk = (const float*)d_in[1];
    const float* qryk = (const float*)d_in[2];
    const float* valk = (const float*)d_in[3];
    const float* ffk  = (const float*)d_in[4];
    const float* g1   = (const float*)d_in[5];
    const float* b1   = (const float*)d_in[6];
    const float* g2   = (const float*)d_in[7];
    const float* b2   = (const float*)d_in[8];
    float* out = (float*)d_out;

    float* ws   = (float*)d_ws;
    float* qs   = ws;                         // 32768 floats
    float* ks   = ws + 32768;                 // 32768
    float* kmx  = ws + 65536;                 // 16
    float* kmn  = ws + 65552;                 // 16
    unsigned short* vT = (unsigned short*)(ws + 65568);   // 2,097,152 bf16
    float* zpre = ws + 65568 + 1048576;       // 2,097,152 floats
    // Zb OVERLAYS vT: vT is dead after attn_kernel; stream order makes this
    // deterministic (qkvT writes vT -> attn reads vT -> ln1 overwrites as Zb).
    unsigned short* Zb  = vT;                               // 2,097,152 bf16
    unsigned short* WbT = (unsigned short*)(ws + 65568 + 1048576 + 2097152); // 262,144 bf16

    qkvT_kernel<<<B*T/4, 256, 0, stream>>>(emb, qryk, keyk, valk, qs, ks, vT);
    minmax_kernel<<<B*H, 256, 0, stream>>>(ks, kmx, kmn);
    attn_kernel<<<B*H*(T/64), 256, 0, stream>>>(qs, ks, kmx, kmn, vT, emb, zpre);
    ln1_kernel<<<B*H*T/4, 256, 0, stream>>>(zpre, g1, b1, Zb);
    wcvt_kernel<<<H*H, 256, 0, stream>>>(ffk, WbT);
    ffn_gemm_kernel<<<(B*T/64)*H, 256, 0, stream>>>(Zb, WbT, g2, b2, out);
}

// Round 12
// 76.076 us; speedup vs baseline: 5.0520x; 1.3205x over previous
//
#include <hip/hip_runtime.h>
#include <math.h>

#define T 2048
#define E 64
#define H 8
#define B 2

typedef __attribute__((ext_vector_type(4))) float f32x4;
typedef __attribute__((ext_vector_type(8))) short s16x8;

static __device__ __forceinline__ unsigned short f2bf(float x) {
    union { float f; unsigned u; } v; v.f = x;
    unsigned r = v.u + 0x7FFFu + ((v.u >> 16) & 1u);   // RNE
    return (unsigned short)(r >> 16);
}
static __device__ __forceinline__ float bf2f(unsigned short u) {
    union { unsigned u; float f; } v; v.u = ((unsigned)u) << 16;
    return v.f;
}

// ---------------------------------------------------------------------------
// K1 (rebuilt): block = (one head h, 64 tokens).  vk[h] staged ONCE into LDS
// transposed wkT[f][e] (+pad); emb tile in LDS; inner loop is pure LDS+FMA.
// Output transposed via XOR-swizzled LDS vtile -> 128B-contiguous global
// writes.  Kills both the 128MB vk re-read and the 4x write amplification.
// ---------------------------------------------------------------------------
__global__ __launch_bounds__(256) void qkvT_kernel(
    const float* __restrict__ emb,   // [B,T,E]
    const float* __restrict__ qk,    // [H,E]
    const float* __restrict__ kk,    // [H,E]
    const float* __restrict__ vk,    // [H,E,E]
    float* __restrict__ qs,          // [B*H,T]
    float* __restrict__ ks,          // [B*H,T]
    unsigned short* __restrict__ vT) // [B*H,E(f),T] bf16
{
    int h  = blockIdx.x & 7;
    int tc = blockIdx.x >> 3;            // 0..63
    int b  = tc >> 5;
    int t0 = (tc & 31) * 64;
    int tid = threadIdx.x;

    __shared__ __align__(16) float eL[64][64];            // 16 KB
    __shared__ __align__(16) float wkT[64*68];            // [f][e] padded, 17.4 KB
    __shared__ __align__(16) unsigned short vtile[4096];  // [64 f][64 t] swz, 8 KB

    // stage emb tile (coalesced)
    #pragma unroll
    for (int i = 0; i < 4; ++i) {
        int s = tid + i*256;             // float4 slot 0..1023
        int t = s >> 4, e4 = s & 15;
        ((float4*)&eL[t][0])[e4] = ((const float4*)(emb + ((long)b*T + t0 + t)*E))[e4];
    }
    // stage vk[h] transposed -> wkT[f][e]  (read coalesced, scatter to LDS)
    const float* vkh = vk + h*4096;
    #pragma unroll
    for (int i = 0; i < 16; ++i) {
        int s = tid + i*256;
        int e = s >> 6, f = s & 63;
        wkT[f*68 + e] = vkh[e*64 + f];
    }
    __syncthreads();

    // scores: 64 tokens x {q,k} (128 dots of 64); +t stagger spreads banks
    if (tid < 128) {
        int t = tid & 63, sel = tid >> 6;
        const float* wp = (sel ? kk : qk) + h*64;
        float s = 0.f;
        #pragma unroll
        for (int e = 0; e < 64; ++e) {
            int ei = (e + t) & 63;
            s += eL[t][ei] * wp[ei];
        }
        float* dst = sel ? ks : qs;
        dst[((long)b*H + h)*T + t0 + t] = s;
    }

    // V projection: lane f = tid&63, wave wv = tid>>6 owns t-chunks wv, wv+4
    int f  = tid & 63;
    int wv = tid >> 6;
    float acc[2][8];
    #pragma unroll
    for (int hf2 = 0; hf2 < 2; ++hf2)
        #pragma unroll
        for (int i = 0; i < 8; ++i) acc[hf2][i] = 0.f;

    #pragma unroll 4
    for (int e4 = 0; e4 < 16; ++e4) {
        float4 w4 = *(const float4*)&wkT[f*68 + e4*4];   // per-lane f: spread
        #pragma unroll
        for (int half = 0; half < 2; ++half) {
            int tb = half*32 + wv*8;
            #pragma unroll
            for (int i = 0; i < 8; ++i) {
                float4 ev = *(const float4*)&eL[tb + i][e4*4];  // wave-uniform: broadcast
                acc[half][i] += ev.x*w4.x + ev.y*w4.y + ev.z*w4.z + ev.w*w4.w;
            }
        }
    }

    // pack -> swizzled vtile (b128, conflict-free)
    #pragma unroll
    for (int half = 0; half < 2; ++half) {
        int c = wv + half*4;             // t-chunk 0..7
        s16x8 o;
        #pragma unroll
        for (int i = 0; i < 8; ++i) o[i] = (short)f2bf(acc[half][i]);
        *(s16x8*)&vtile[f*64 + ((c ^ (f & 7)) * 8)] = o;
    }
    __syncthreads();

    // coalesced writeout: 8 lanes per f-row -> 128B contiguous
    long rowbase = ((long)(b*H + h)*64) * (long)T;
    #pragma unroll
    for (int i = 0; i < 2; ++i) {
        int s = tid + i*256;             // 0..511
        int fo = s >> 3, c = s & 7;
        s16x8 v = *(const s16x8*)&vtile[fo*64 + ((c ^ (fo & 7)) * 8)];
        *(s16x8*)(vT + rowbase + (long)fo*T + t0 + c*8) = v;
    }
}

// ---------------------------------------------------------------------------
// K2: per-(b,h) min/max of ks (exact softmax max for rank-1 scores)
// ---------------------------------------------------------------------------
__global__ __launch_bounds__(256) void minmax_kernel(
    const float* __restrict__ ks, float* __restrict__ kmax, float* __restrict__ kmin)
{
    int bh = blockIdx.x;
    int tid = threadIdx.x;
    float mx = -1e30f, mn = 1e30f;
    for (int i = tid; i < T; i += 256) {
        float x = ks[(long)bh*T + i];
        mx = fmaxf(mx, x); mn = fminf(mn, x);
    }
    __shared__ float smx[256], smn[256];
    smx[tid] = mx; smn[tid] = mn;
    __syncthreads();
    for (int s = 128; s > 0; s >>= 1) {
        if (tid < s) {
            smx[tid] = fmaxf(smx[tid], smx[tid+s]);
            smn[tid] = fminf(smn[tid], smn[tid+s]);
        }
        __syncthreads();
    }
    if (tid == 0) { kmax[bh] = smx[0]; kmin[bh] = smn[0]; }
}

// ---------------------------------------------------------------------------
// K3: attention via MFMA, double-buffered V staging (unchanged from round 10)
// ---------------------------------------------------------------------------
__global__ __launch_bounds__(256) void attn_kernel(
    const float* __restrict__ qs, const float* __restrict__ ksg,
    const float* __restrict__ kmax, const float* __restrict__ kmin,
    const unsigned short* __restrict__ vT, const float* __restrict__ emb,
    float* __restrict__ zpre)
{
    int bh = blockIdx.x >> 5;            // 0..15
    int q0 = (blockIdx.x & 31) * 64;
    int b  = bh >> 3;
    int tid = threadIdx.x;
    int w = tid >> 6, l = tid & 63;
    int g = l >> 4, r = l & 15;

    __shared__ __align__(16) float ksL[2048];              // 8 KB
    __shared__ __align__(16) unsigned short VtL[2][8192];  // 2x[64 f][128 k] swz, 32 KB

    ((float4*)ksL)[tid]       = ((const float4*)(ksg + (long)bh*T))[tid];
    ((float4*)ksL)[tid + 256] = ((const float4*)(ksg + (long)bh*T))[tid + 256];

    float sreg, mreg;
    {
        float s = qs[(long)bh*T + q0 + w*16 + r];
        sreg = s;
        mreg = (s >= 0.f) ? s*kmax[bh] : s*kmin[bh];
    }

    // prologue: stage chunk 0 into VtL[0]
    #pragma unroll
    for (int j = 0; j < 4; ++j) {
        int i = tid + j*256;             // 16B-slot 0..1023
        int f = i >> 4, si = i & 15;
        s16x8 val = *(const s16x8*)(vT + ((long)(bh*64 + f))*T + si*8);
        *(s16x8*)&VtL[0][f*128 + ((si ^ (f & 15)) * 8)] = val;
    }
    __syncthreads();                     // ksL + chunk0 visible

    f32x4 acc[4] = {{0.f,0.f,0.f,0.f},{0.f,0.f,0.f,0.f},
                    {0.f,0.f,0.f,0.f},{0.f,0.f,0.f,0.f}};
    float dsum = 0.f;

    for (int kc = 0; kc < 16; ++kc) {
        int cur = kc & 1;
        // issue prefetch loads for next chunk (latency hides under compute)
        s16x8 pf[4];
        if (kc < 15) {
            #pragma unroll
            for (int j = 0; j < 4; ++j) {
                int i = tid + j*256;
                int f = i >> 4, si = i & 15;
                pf[j] = *(const s16x8*)(vT + ((long)(bh*64 + f))*T + (kc+1)*128 + si*8);
            }
        }
        // compute chunk kc from VtL[cur]
        #pragma unroll
        for (int kw = 0; kw < 4; ++kw) { // 32-k MFMA windows
            int kbase = kc*128 + kw*32 + g*8;
            float4 ka = *(const float4*)&ksL[kbase];
            float4 kb = *(const float4*)&ksL[kbase + 4];
            float p0 = __expf(fmaf(sreg, ka.x, -mreg));
            float p1 = __expf(fmaf(sreg, ka.y, -mreg));
            float p2 = __expf(fmaf(sreg, ka.z, -mreg));
            float p3 = __expf(fmaf(sreg, ka.w, -mreg));
            float p4 = __expf(fmaf(sreg, kb.x, -mreg));
            float p5 = __expf(fmaf(sreg, kb.y, -mreg));
            float p6 = __expf(fmaf(sreg, kb.z, -mreg));
            float p7 = __expf(fmaf(sreg, kb.w, -mreg));
            dsum += ((p0+p1)+(p2+p3)) + ((p4+p5)+(p6+p7));
            s16x8 af;
            af[0] = (short)f2bf(p0); af[1] = (short)f2bf(p1);
            af[2] = (short)f2bf(p2); af[3] = (short)f2bf(p3);
            af[4] = (short)f2bf(p4); af[5] = (short)f2bf(p5);
            af[6] = (short)f2bf(p6); af[7] = (short)f2bf(p7);
            int slot = kw*4 + g;
            #pragma unroll
            for (int ct = 0; ct < 4; ++ct) {
                s16x8 bf = *(const s16x8*)&VtL[cur][(ct*16 + r)*128 + ((slot ^ r) * 8)];
                acc[ct] = __builtin_amdgcn_mfma_f32_16x16x32_bf16(af, bf, acc[ct], 0, 0, 0);
            }
        }
        // write prefetched chunk to the other buffer
        if (kc < 15) {
            #pragma unroll
            for (int j = 0; j < 4; ++j) {
                int i = tid + j*256;
                int f = i >> 4, si = i & 15;
                *(s16x8*)&VtL[cur ^ 1][f*128 + ((si ^ (f & 15)) * 8)] = pf[j];
            }
        }
        __syncthreads();                 // next-chunk staging visible
    }

    // full row-denominator into every lane (per its A-row r)
    dsum += __shfl_xor(dsum, 16, 64);
    dsum += __shfl_xor(dsum, 32, 64);

    #pragma unroll
    for (int i = 0; i < 4; ++i) {
        int lrow = g*4 + i;               // C layout: local row=(lane>>4)*4+i
        float den = __shfl(dsum, lrow, 16);  // lane 16*g+lrow holds row lrow's den
        float inv = 1.f / den;
        long q = q0 + w*16 + lrow;
        const float* erow = emb + ((long)b*T + q)*E;
        #pragma unroll
        for (int ct = 0; ct < 4; ++ct) {
            int f = ct*16 + r;
            zpre[((long)bh*T + q)*E + f] = erow[f] + acc[ct][i] * inv;
        }
    }
}

// ---------------------------------------------------------------------------
// K4a: LN1 over zpre rows of 64, output Z bf16 in GEMM layout:
//      Zb[token = b*T+t][h*64+e].  Wave per row, shfl butterfly reduce.
// ---------------------------------------------------------------------------
__global__ __launch_bounds__(256) void ln1_kernel(
    const float* __restrict__ zpre,  // [B*H,T,64]
    const float* __restrict__ g1, const float* __restrict__ b1,
    unsigned short* __restrict__ Zb) // [B*T,512] bf16
{
    int row  = blockIdx.x*4 + (threadIdx.x >> 6);  // bh*T + t, 0..32767
    int lane = threadIdx.x & 63;
    float x = zpre[(long)row*64 + lane];
    float s = x, s2 = x*x;
    #pragma unroll
    for (int o = 1; o < 64; o <<= 1) {
        s  += __shfl_xor(s,  o, 64);
        s2 += __shfl_xor(s2, o, 64);
    }
    float mu  = s * (1.f/64.f);
    float var = s2 * (1.f/64.f) - mu*mu;
    float rs  = rsqrtf(var + 1e-3f);
    float zn  = g1[lane]*(x - mu)*rs + b1[lane];
    int b = row >> 14, h = (row >> 11) & 7, t = row & 2047;
    long token = (long)b*T + t;
    Zb[token*512 + h*64 + lane] = f2bf(zn);
}

// ---------------------------------------------------------------------------
// K4b: weight transpose+cast: fk[h,g,e,f] fp32 -> WbT[n=g*64+f][k=h*64+e] bf16
// ---------------------------------------------------------------------------
__global__ __launch_bounds__(256) void wcvt_kernel(
    const float* __restrict__ fk, unsigned short* __restrict__ WbT)
{
    int hg = blockIdx.x;                 // h*8+g
    int h = hg >> 3, g = hg & 7;
    int tid = threadIdx.x;
    __shared__ float wt[64][65];         // padded, 16.6 KB
    const float* src = fk + (long)hg*4096;
    #pragma unroll
    for (int j = 0; j < 4; ++j) {
        int s = tid + j*256;             // float4 slot 0..1023
        int e = s >> 4, f4 = s & 15;
        float4 v = ((const float4*)src)[s];
        wt[e][f4*4+0] = v.x; wt[e][f4*4+1] = v.y;
        wt[e][f4*4+2] = v.z; wt[e][f4*4+3] = v.w;
    }
    __syncthreads();
    #pragma unroll
    for (int j = 0; j < 2; ++j) {
        int s = tid + j*256;             // 16B slot 0..511
        int f = s >> 3, e8 = s & 7;
        s16x8 o;
        #pragma unroll
        for (int q = 0; q < 8; ++q) o[q] = (short)f2bf(wt[e8*8+q][f]);
        *(s16x8*)(WbT + ((long)(g*64+f))*512 + h*64 + e8*8) = o;
    }
}

// ---------------------------------------------------------------------------
// K4c: FFN GEMM via MFMA + fused residual/gelu/LN2 epilogue (unchanged).
// ---------------------------------------------------------------------------
__global__ __launch_bounds__(256) void ffn_gemm_kernel(
    const unsigned short* __restrict__ Zb,   // [4096][512] bf16
    const unsigned short* __restrict__ WbT,  // [512 n][512 k] bf16
    const float* __restrict__ g2, const float* __restrict__ b2,
    float* __restrict__ out)                 // [B,G,T,F]
{
    int bm = blockIdx.x >> 3;            // 0..63 token block
    int g  = blockIdx.x & 7;             // output head block
    int m0 = bm*64;
    int tid = threadIdx.x;
    int w = tid >> 6, l = tid & 63;
    int lg = l >> 4, r = l & 15;
    int wr = w >> 1, wc = w & 1;

    __shared__ __align__(16) unsigned short As[4096];  // [64 m][64 k] swz, 8 KB
    __shared__ __align__(16) unsigned short Bs[4096];  // [64 n][64 k] swz, 8 KB
    __shared__ float yL[64][68];                       // C tile, 17.4 KB

    f32x4 acc[2][2] = {{{0.f,0.f,0.f,0.f},{0.f,0.f,0.f,0.f}},
                       {{0.f,0.f,0.f,0.f},{0.f,0.f,0.f,0.f}}};

    for (int kc = 0; kc < 8; ++kc) {
        #pragma unroll
        for (int j = 0; j < 2; ++j) {
            int s = tid + j*256;         // 16B slot 0..511
            int row = s >> 3, c16 = s & 7;
            s16x8 va = *(const s16x8*)(Zb  + ((long)(m0 + row))*512   + kc*64 + c16*8);
            s16x8 vb = *(const s16x8*)(WbT + ((long)(g*64 + row))*512 + kc*64 + c16*8);
            *(s16x8*)&As[row*64 + ((c16 ^ (row & 7))*8)] = va;
            *(s16x8*)&Bs[row*64 + ((c16 ^ (row & 7))*8)] = vb;
        }
        __syncthreads();
        #pragma unroll
        for (int kk = 0; kk < 2; ++kk) {
            s16x8 af[2], bf[2];
            #pragma unroll
            for (int mi = 0; mi < 2; ++mi) {
                int row = wr*32 + mi*16 + r;
                af[mi] = *(const s16x8*)&As[row*64 + (((kk*4 + lg) ^ (row & 7))*8)];
            }
            #pragma unroll
            for (int ni = 0; ni < 2; ++ni) {
                int row = wc*32 + ni*16 + r;
                bf[ni] = *(const s16x8*)&Bs[row*64 + (((kk*4 + lg) ^ (row & 7))*8)];
            }
            #pragma unroll
            for (int mi = 0; mi < 2; ++mi)
                #pragma unroll
                for (int ni = 0; ni < 2; ++ni)
                    acc[mi][ni] = __builtin_amdgcn_mfma_f32_16x16x32_bf16(
                        af[mi], bf[ni], acc[mi][ni], 0, 0, 0);
        }
        __syncthreads();
    }

    // scatter C to yL (C layout: col=lane&15, row=(lane>>4)*4+i)
    #pragma unroll
    for (int mi = 0; mi < 2; ++mi)
        #pragma unroll
        for (int ni = 0; ni < 2; ++ni)
            #pragma unroll
            for (int i = 0; i < 4; ++i)
                yL[wr*32 + mi*16 + lg*4 + i][wc*32 + ni*16 + r] = acc[mi][ni][i];
    __syncthreads();

    // residual + gelu + LN2: quad of lanes per token row (4 x 16 elems)
    int rowt = tid >> 2, part = tid & 3;
    const unsigned short* zrow = Zb + ((long)(m0 + rowt))*512 + g*64 + part*16;
    s16x8 z0 = *(const s16x8*)zrow;
    s16x8 z1 = *(const s16x8*)(zrow + 8);
    const float kg = 0.7978845608028654f;
    float y[16];
    float s = 0.f, s2 = 0.f;
    #pragma unroll
    for (int q = 0; q < 16; ++q) {
        float zn = bf2f((unsigned short)(q < 8 ? z0[q] : z1[q-8]));
        float x = zn + yL[rowt][part*16 + q];
        x = 0.5f*x*(1.f + tanhf(kg*(x + 0.044715f*x*x*x)));
        y[q] = x; s += x; s2 += x*x;
    }
    s  += __shfl_xor(s,  1, 64);  s  += __shfl_xor(s,  2, 64);
    s2 += __shfl_xor(s2, 1, 64);  s2 += __shfl_xor(s2, 2, 64);
    float mu  = s * (1.f/64.f);
    float var = s2 * (1.f/64.f) - mu*mu;
    float rs  = rsqrtf(var + 1e-3f);

    int token = m0 + rowt;
    int b = token >> 11, t = token & 2047;
    long ob = (((long)(b*H + g))*T + t)*64 + part*16;
    #pragma unroll
    for (int q = 0; q < 16; ++q) {
        int f = part*16 + q;
        y[q] = g2[f]*(y[q] - mu)*rs + b2[f];
    }
    #pragma unroll
    for (int q = 0; q < 4; ++q) {
        float4 o = { y[q*4], y[q*4+1], y[q*4+2], y[q*4+3] };
        *(float4*)(out + ob + q*4) = o;
    }
}

// ---------------------------------------------------------------------------
extern "C" void kernel_launch(void* const* d_in, const int* in_sizes, int n_in,
                              void* d_out, int out_size, void* d_ws, size_t ws_size,
                              hipStream_t stream) {
    const float* emb  = (const float*)d_in[0];
    const float* keyk = (const float*)d_in[1];
    const float* qryk = (const float*)d_in[2];
    const float* valk = (const float*)d_in[3];
    const float* ffk  = (const float*)d_in[4];
    const float* g1   = (const float*)d_in[5];
    const float* b1   = (const float*)d_in[6];
    const float* g2   = (const float*)d_in[7];
    const float* b2   = (const float*)d_in[8];
    float* out = (float*)d_out;

    float* ws   = (float*)d_ws;
    float* qs   = ws;                         // 32768 floats
    float* ks   = ws + 32768;                 // 32768
    float* kmx  = ws + 65536;                 // 16
    float* kmn  = ws + 65552;                 // 16
    unsigned short* vT = (unsigned short*)(ws + 65568);   // 2,097,152 bf16
    float* zpre = ws + 65568 + 1048576;       // 2,097,152 floats
    // Zb OVERLAYS vT: vT is dead after attn_kernel; stream order makes this
    // deterministic (qkvT writes vT -> attn reads vT -> ln1 overwrites as Zb).
    unsigned short* Zb  = vT;                               // 2,097,152 bf16
    unsigned short* WbT = (unsigned short*)(ws + 65568 + 1048576 + 2097152); // 262,144 bf16

    qkvT_kernel<<<(B*T/64)*H, 256, 0, stream>>>(emb, qryk, keyk, valk, qs, ks, vT);
    minmax_kernel<<<B*H, 256, 0, stream>>>(ks, kmx, kmn);
    attn_kernel<<<B*H*(T/64), 256, 0, stream>>>(qs, ks, kmx, kmn, vT, emb, zpre);
    ln1_kernel<<<B*H*T/4, 256, 0, stream>>>(zpre, g1, b1, Zb);
    wcvt_kernel<<<H*H, 256, 0, stream>>>(ffk, WbT);
    ffn_gemm_kernel<<<(B*T/64)*H, 256, 0, stream>>>(Zb, WbT, g2, b2, out);
}

// Round 13
// 73.544 us; speedup vs baseline: 5.2260x; 1.0344x over previous
//
#include <hip/hip_runtime.h>
#include <math.h>

#define T 2048
#define E 64
#define H 8
#define B 2

typedef __attribute__((ext_vector_type(4))) float f32x4;
typedef __attribute__((ext_vector_type(8))) short s16x8;

static __device__ __forceinline__ unsigned short f2bf(float x) {
    union { float f; unsigned u; } v; v.f = x;
    unsigned r = v.u + 0x7FFFu + ((v.u >> 16) & 1u);   // RNE
    return (unsigned short)(r >> 16);
}
static __device__ __forceinline__ float bf2f(unsigned short u) {
    union { unsigned u; float f; } v; v.u = ((unsigned)u) << 16;
    return v.f;
}
// packed bf16 convert: low short = lo, high short = hi (RNE, HW cvt)
// [bisection: this is round-8 suspect (b), reintroduced ALONE this round]
static __device__ __forceinline__ unsigned pk_bf16(float lo, float hi) {
    unsigned r;
    asm("v_cvt_pk_bf16_f32 %0, %1, %2" : "=v"(r) : "v"(lo), "v"(hi));
    return r;
}

// ---------------------------------------------------------------------------
// K1: block = (one head h, 64 tokens).  vk[h] staged ONCE into LDS transposed
// wkT[f][e] (+pad); emb tile in LDS; inner loop pure LDS+FMA.  Output via
// XOR-swizzled LDS vtile -> 128B-contiguous global writes.  (unchanged)
// ---------------------------------------------------------------------------
__global__ __launch_bounds__(256) void qkvT_kernel(
    const float* __restrict__ emb,   // [B,T,E]
    const float* __restrict__ qk,    // [H,E]
    const float* __restrict__ kk,    // [H,E]
    const float* __restrict__ vk,    // [H,E,E]
    float* __restrict__ qs,          // [B*H,T]
    float* __restrict__ ks,          // [B*H,T]
    unsigned short* __restrict__ vT) // [B*H,E(f),T] bf16
{
    int h  = blockIdx.x & 7;
    int tc = blockIdx.x >> 3;            // 0..63
    int b  = tc >> 5;
    int t0 = (tc & 31) * 64;
    int tid = threadIdx.x;

    __shared__ __align__(16) float eL[64][64];            // 16 KB
    __shared__ __align__(16) float wkT[64*68];            // [f][e] padded, 17.4 KB
    __shared__ __align__(16) unsigned short vtile[4096];  // [64 f][64 t] swz, 8 KB

    // stage emb tile (coalesced)
    #pragma unroll
    for (int i = 0; i < 4; ++i) {
        int s = tid + i*256;             // float4 slot 0..1023
        int t = s >> 4, e4 = s & 15;
        ((float4*)&eL[t][0])[e4] = ((const float4*)(emb + ((long)b*T + t0 + t)*E))[e4];
    }
    // stage vk[h] transposed -> wkT[f][e]  (read coalesced, scatter to LDS)
    const float* vkh = vk + h*4096;
    #pragma unroll
    for (int i = 0; i < 16; ++i) {
        int s = tid + i*256;
        int e = s >> 6, f = s & 63;
        wkT[f*68 + e] = vkh[e*64 + f];
    }
    __syncthreads();

    // scores: 64 tokens x {q,k} (128 dots of 64); +t stagger spreads banks
    if (tid < 128) {
        int t = tid & 63, sel = tid >> 6;
        const float* wp = (sel ? kk : qk) + h*64;
        float s = 0.f;
        #pragma unroll
        for (int e = 0; e < 64; ++e) {
            int ei = (e + t) & 63;
            s += eL[t][ei] * wp[ei];
        }
        float* dst = sel ? ks : qs;
        dst[((long)b*H + h)*T + t0 + t] = s;
    }

    // V projection: lane f = tid&63, wave wv = tid>>6 owns t-chunks wv, wv+4
    int f  = tid & 63;
    int wv = tid >> 6;
    float acc[2][8];
    #pragma unroll
    for (int hf2 = 0; hf2 < 2; ++hf2)
        #pragma unroll
        for (int i = 0; i < 8; ++i) acc[hf2][i] = 0.f;

    #pragma unroll 4
    for (int e4 = 0; e4 < 16; ++e4) {
        float4 w4 = *(const float4*)&wkT[f*68 + e4*4];   // per-lane f: spread
        #pragma unroll
        for (int half = 0; half < 2; ++half) {
            int tb = half*32 + wv*8;
            #pragma unroll
            for (int i = 0; i < 8; ++i) {
                float4 ev = *(const float4*)&eL[tb + i][e4*4];  // wave-uniform: broadcast
                acc[half][i] += ev.x*w4.x + ev.y*w4.y + ev.z*w4.z + ev.w*w4.w;
            }
        }
    }

    // pack -> swizzled vtile (b128, conflict-free)
    #pragma unroll
    for (int half = 0; half < 2; ++half) {
        int c = wv + half*4;             // t-chunk 0..7
        s16x8 o;
        #pragma unroll
        for (int i = 0; i < 8; ++i) o[i] = (short)f2bf(acc[half][i]);
        *(s16x8*)&vtile[f*64 + ((c ^ (f & 7)) * 8)] = o;
    }
    __syncthreads();

    // coalesced writeout: 8 lanes per f-row -> 128B contiguous
    long rowbase = ((long)(b*H + h)*64) * (long)T;
    #pragma unroll
    for (int i = 0; i < 2; ++i) {
        int s = tid + i*256;             // 0..511
        int fo = s >> 3, c = s & 7;
        s16x8 v = *(const s16x8*)&vtile[fo*64 + ((c ^ (fo & 7)) * 8)];
        *(s16x8*)(vT + rowbase + (long)fo*T + t0 + c*8) = v;
    }
}

// ---------------------------------------------------------------------------
// K2: per-(b,h) min/max of ks (exact softmax max for rank-1 scores)
// ---------------------------------------------------------------------------
__global__ __launch_bounds__(256) void minmax_kernel(
    const float* __restrict__ ks, float* __restrict__ kmax, float* __restrict__ kmin)
{
    int bh = blockIdx.x;
    int tid = threadIdx.x;
    float mx = -1e30f, mn = 1e30f;
    for (int i = tid; i < T; i += 256) {
        float x = ks[(long)bh*T + i];
        mx = fmaxf(mx, x); mn = fminf(mn, x);
    }
    __shared__ float smx[256], smn[256];
    smx[tid] = mx; smn[tid] = mn;
    __syncthreads();
    for (int s = 128; s > 0; s >>= 1) {
        if (tid < s) {
            smx[tid] = fmaxf(smx[tid], smx[tid+s]);
            smn[tid] = fminf(smn[tid], smn[tid+s]);
        }
        __syncthreads();
    }
    if (tid == 0) { kmax[bh] = smx[0]; kmin[bh] = smn[0]; }
}

// ---------------------------------------------------------------------------
// K3: attention via MFMA, double-buffered V staging.  ONLY change vs the
// round-12 measured source: P pack uses v_cvt_pk_bf16_f32 (4 instr/window
// instead of ~36 manual-RNE instr).
// ---------------------------------------------------------------------------
__global__ __launch_bounds__(256) void attn_kernel(
    const float* __restrict__ qs, const float* __restrict__ ksg,
    const float* __restrict__ kmax, const float* __restrict__ kmin,
    const unsigned short* __restrict__ vT, const float* __restrict__ emb,
    float* __restrict__ zpre)
{
    int bh = blockIdx.x >> 5;            // 0..15
    int q0 = (blockIdx.x & 31) * 64;
    int b  = bh >> 3;
    int tid = threadIdx.x;
    int w = tid >> 6, l = tid & 63;
    int g = l >> 4, r = l & 15;

    __shared__ __align__(16) float ksL[2048];              // 8 KB
    __shared__ __align__(16) unsigned short VtL[2][8192];  // 2x[64 f][128 k] swz, 32 KB

    ((float4*)ksL)[tid]       = ((const float4*)(ksg + (long)bh*T))[tid];
    ((float4*)ksL)[tid + 256] = ((const float4*)(ksg + (long)bh*T))[tid + 256];

    float sreg, mreg;
    {
        float s = qs[(long)bh*T + q0 + w*16 + r];
        sreg = s;
        mreg = (s >= 0.f) ? s*kmax[bh] : s*kmin[bh];
    }

    // prologue: stage chunk 0 into VtL[0]
    #pragma unroll
    for (int j = 0; j < 4; ++j) {
        int i = tid + j*256;             // 16B-slot 0..1023
        int f = i >> 4, si = i & 15;
        s16x8 val = *(const s16x8*)(vT + ((long)(bh*64 + f))*T + si*8);
        *(s16x8*)&VtL[0][f*128 + ((si ^ (f & 15)) * 8)] = val;
    }
    __syncthreads();                     // ksL + chunk0 visible

    f32x4 acc[4] = {{0.f,0.f,0.f,0.f},{0.f,0.f,0.f,0.f},
                    {0.f,0.f,0.f,0.f},{0.f,0.f,0.f,0.f}};
    float dsum = 0.f;

    for (int kc = 0; kc < 16; ++kc) {
        int cur = kc & 1;
        // issue prefetch loads for next chunk (latency hides under compute)
        s16x8 pf[4];
        if (kc < 15) {
            #pragma unroll
            for (int j = 0; j < 4; ++j) {
                int i = tid + j*256;
                int f = i >> 4, si = i & 15;
                pf[j] = *(const s16x8*)(vT + ((long)(bh*64 + f))*T + (kc+1)*128 + si*8);
            }
        }
        // compute chunk kc from VtL[cur]
        #pragma unroll
        for (int kw = 0; kw < 4; ++kw) { // 32-k MFMA windows
            int kbase = kc*128 + kw*32 + g*8;
            float4 ka = *(const float4*)&ksL[kbase];
            float4 kb = *(const float4*)&ksL[kbase + 4];
            float p0 = __expf(fmaf(sreg, ka.x, -mreg));
            float p1 = __expf(fmaf(sreg, ka.y, -mreg));
            float p2 = __expf(fmaf(sreg, ka.z, -mreg));
            float p3 = __expf(fmaf(sreg, ka.w, -mreg));
            float p4 = __expf(fmaf(sreg, kb.x, -mreg));
            float p5 = __expf(fmaf(sreg, kb.y, -mreg));
            float p6 = __expf(fmaf(sreg, kb.z, -mreg));
            float p7 = __expf(fmaf(sreg, kb.w, -mreg));
            dsum += ((p0+p1)+(p2+p3)) + ((p4+p5)+(p6+p7));
            union { s16x8 v; unsigned u[4]; } af;
            af.u[0] = pk_bf16(p0, p1);
            af.u[1] = pk_bf16(p2, p3);
            af.u[2] = pk_bf16(p4, p5);
            af.u[3] = pk_bf16(p6, p7);
            int slot = kw*4 + g;
            #pragma unroll
            for (int ct = 0; ct < 4; ++ct) {
                s16x8 bf = *(const s16x8*)&VtL[cur][(ct*16 + r)*128 + ((slot ^ r) * 8)];
                acc[ct] = __builtin_amdgcn_mfma_f32_16x16x32_bf16(af.v, bf, acc[ct], 0, 0, 0);
            }
        }
        // write prefetched chunk to the other buffer
        if (kc < 15) {
            #pragma unroll
            for (int j = 0; j < 4; ++j) {
                int i = tid + j*256;
                int f = i >> 4, si = i & 15;
                *(s16x8*)&VtL[cur ^ 1][f*128 + ((si ^ (f & 15)) * 8)] = pf[j];
            }
        }
        __syncthreads();                 // next-chunk staging visible
    }

    // full row-denominator into every lane (per its A-row r)
    dsum += __shfl_xor(dsum, 16, 64);
    dsum += __shfl_xor(dsum, 32, 64);

    #pragma unroll
    for (int i = 0; i < 4; ++i) {
        int lrow = g*4 + i;               // C layout: local row=(lane>>4)*4+i
        float den = __shfl(dsum, lrow, 16);  // lane 16*g+lrow holds row lrow's den
        float inv = 1.f / den;
        long q = q0 + w*16 + lrow;
        const float* erow = emb + ((long)b*T + q)*E;
        #pragma unroll
        for (int ct = 0; ct < 4; ++ct) {
            int f = ct*16 + r;
            zpre[((long)bh*T + q)*E + f] = erow[f] + acc[ct][i] * inv;
        }
    }
}

// ---------------------------------------------------------------------------
// K4a: LN1 over zpre rows of 64, output Z bf16 in GEMM layout (unchanged).
// ---------------------------------------------------------------------------
__global__ __launch_bounds__(256) void ln1_kernel(
    const float* __restrict__ zpre,  // [B*H,T,64]
    const float* __restrict__ g1, const float* __restrict__ b1,
    unsigned short* __restrict__ Zb) // [B*T,512] bf16
{
    int row  = blockIdx.x*4 + (threadIdx.x >> 6);  // bh*T + t, 0..32767
    int lane = threadIdx.x & 63;
    float x = zpre[(long)row*64 + lane];
    float s = x, s2 = x*x;
    #pragma unroll
    for (int o = 1; o < 64; o <<= 1) {
        s  += __shfl_xor(s,  o, 64);
        s2 += __shfl_xor(s2, o, 64);
    }
    float mu  = s * (1.f/64.f);
    float var = s2 * (1.f/64.f) - mu*mu;
    float rs  = rsqrtf(var + 1e-3f);
    float zn  = g1[lane]*(x - mu)*rs + b1[lane];
    int b = row >> 14, h = (row >> 11) & 7, t = row & 2047;
    long token = (long)b*T + t;
    Zb[token*512 + h*64 + lane] = f2bf(zn);
}

// ---------------------------------------------------------------------------
// K4b: weight transpose+cast: fk[h,g,e,f] fp32 -> WbT[n=g*64+f][k=h*64+e] bf16
// ---------------------------------------------------------------------------
__global__ __launch_bounds__(256) void wcvt_kernel(
    const float* __restrict__ fk, unsigned short* __restrict__ WbT)
{
    int hg = blockIdx.x;                 // h*8+g
    int h = hg >> 3, g = hg & 7;
    int tid = threadIdx.x;
    __shared__ float wt[64][65];         // padded, 16.6 KB
    const float* src = fk + (long)hg*4096;
    #pragma unroll
    for (int j = 0; j < 4; ++j) {
        int s = tid + j*256;             // float4 slot 0..1023
        int e = s >> 4, f4 = s & 15;
        float4 v = ((const float4*)src)[s];
        wt[e][f4*4+0] = v.x; wt[e][f4*4+1] = v.y;
        wt[e][f4*4+2] = v.z; wt[e][f4*4+3] = v.w;
    }
    __syncthreads();
    #pragma unroll
    for (int j = 0; j < 2; ++j) {
        int s = tid + j*256;             // 16B slot 0..511
        int f = s >> 3, e8 = s & 7;
        s16x8 o;
        #pragma unroll
        for (int q = 0; q < 8; ++q) o[q] = (short)f2bf(wt[e8*8+q][f]);
        *(s16x8*)(WbT + ((long)(g*64+f))*512 + h*64 + e8*8) = o;
    }
}

// ---------------------------------------------------------------------------
// K4c: FFN GEMM via MFMA + fused residual/gelu/LN2 epilogue (unchanged).
// ---------------------------------------------------------------------------
__global__ __launch_bounds__(256) void ffn_gemm_kernel(
    const unsigned short* __restrict__ Zb,   // [4096][512] bf16
    const unsigned short* __restrict__ WbT,  // [512 n][512 k] bf16
    const float* __restrict__ g2, const float* __restrict__ b2,
    float* __restrict__ out)                 // [B,G,T,F]
{
    int bm = blockIdx.x >> 3;            // 0..63 token block
    int g  = blockIdx.x & 7;             // output head block
    int m0 = bm*64;
    int tid = threadIdx.x;
    int w = tid >> 6, l = tid & 63;
    int lg = l >> 4, r = l & 15;
    int wr = w >> 1, wc = w & 1;

    __shared__ __align__(16) unsigned short As[4096];  // [64 m][64 k] swz, 8 KB
    __shared__ __align__(16) unsigned short Bs[4096];  // [64 n][64 k] swz, 8 KB
    __shared__ float yL[64][68];                       // C tile, 17.4 KB

    f32x4 acc[2][2] = {{{0.f,0.f,0.f,0.f},{0.f,0.f,0.f,0.f}},
                       {{0.f,0.f,0.f,0.f},{0.f,0.f,0.f,0.f}}};

    for (int kc = 0; kc < 8; ++kc) {
        #pragma unroll
        for (int j = 0; j < 2; ++j) {
            int s = tid + j*256;         // 16B slot 0..511
            int row = s >> 3, c16 = s & 7;
            s16x8 va = *(const s16x8*)(Zb  + ((long)(m0 + row))*512   + kc*64 + c16*8);
            s16x8 vb = *(const s16x8*)(WbT + ((long)(g*64 + row))*512 + kc*64 + c16*8);
            *(s16x8*)&As[row*64 + ((c16 ^ (row & 7))*8)] = va;
            *(s16x8*)&Bs[row*64 + ((c16 ^ (row & 7))*8)] = vb;
        }
        __syncthreads();
        #pragma unroll
        for (int kk = 0; kk < 2; ++kk) {
            s16x8 af[2], bf[2];
            #pragma unroll
            for (int mi = 0; mi < 2; ++mi) {
                int row = wr*32 + mi*16 + r;
                af[mi] = *(const s16x8*)&As[row*64 + (((kk*4 + lg) ^ (row & 7))*8)];
            }
            #pragma unroll
            for (int ni = 0; ni < 2; ++ni) {
                int row = wc*32 + ni*16 + r;
                bf[ni] = *(const s16x8*)&Bs[row*64 + (((kk*4 + lg) ^ (row & 7))*8)];
            }
            #pragma unroll
            for (int mi = 0; mi < 2; ++mi)
                #pragma unroll
                for (int ni = 0; ni < 2; ++ni)
                    acc[mi][ni] = __builtin_amdgcn_mfma_f32_16x16x32_bf16(
                        af[mi], bf[ni], acc[mi][ni], 0, 0, 0);
        }
        __syncthreads();
    }

    // scatter C to yL (C layout: col=lane&15, row=(lane>>4)*4+i)
    #pragma unroll
    for (int mi = 0; mi < 2; ++mi)
        #pragma unroll
        for (int ni = 0; ni < 2; ++ni)
            #pragma unroll
            for (int i = 0; i < 4; ++i)
                yL[wr*32 + mi*16 + lg*4 + i][wc*32 + ni*16 + r] = acc[mi][ni][i];
    __syncthreads();

    // residual + gelu + LN2: quad of lanes per token row (4 x 16 elems)
    int rowt = tid >> 2, part = tid & 3;
    const unsigned short* zrow = Zb + ((long)(m0 + rowt))*512 + g*64 + part*16;
    s16x8 z0 = *(const s16x8*)zrow;
    s16x8 z1 = *(const s16x8*)(zrow + 8);
    const float kg = 0.7978845608028654f;
    float y[16];
    float s = 0.f, s2 = 0.f;
    #pragma unroll
    for (int q = 0; q < 16; ++q) {
        float zn = bf2f((unsigned short)(q < 8 ? z0[q] : z1[q-8]));
        float x = zn + yL[rowt][part*16 + q];
        x = 0.5f*x*(1.f + tanhf(kg*(x + 0.044715f*x*x*x)));
        y[q] = x; s += x; s2 += x*x;
    }
    s  += __shfl_xor(s,  1, 64);  s  += __shfl_xor(s,  2, 64);
    s2 += __shfl_xor(s2, 1, 64);  s2 += __shfl_xor(s2, 2, 64);
    float mu  = s * (1.f/64.f);
    float var = s2 * (1.f/64.f) - mu*mu;
    float rs  = rsqrtf(var + 1e-3f);

    int token = m0 + rowt;
    int b = token >> 11, t = token & 2047;
    long ob = (((long)(b*H + g))*T + t)*64 + part*16;
    #pragma unroll
    for (int q = 0; q < 16; ++q) {
        int f = part*16 + q;
        y[q] = g2[f]*(y[q] - mu)*rs + b2[f];
    }
    #pragma unroll
    for (int q = 0; q < 4; ++q) {
        float4 o = { y[q*4], y[q*4+1], y[q*4+2], y[q*4+3] };
        *(float4*)(out + ob + q*4) = o;
    }
}

// ---------------------------------------------------------------------------
extern "C" void kernel_launch(void* const* d_in, const int* in_sizes, int n_in,
                              void* d_out, int out_size, void* d_ws, size_t ws_size,
                              hipStream_t stream) {
    const float* emb  = (const float*)d_in[0];
    const float* keyk = (const float*)d_in[1];
    const float* qryk = (const float*)d_in[2];
    const float* valk = (const float*)d_in[3];
    const float* ffk  = (const float*)d_in[4];
    const float* g1   = (const float*)d_in[5];
    const float* b1   = (const float*)d_in[6];
    const float* g2   = (const float*)d_in[7];
    const float* b2   = (const float*)d_in[8];
    float* out = (float*)d_out;

    float* ws   = (float*)d_ws;
    float* qs   = ws;                         // 32768 floats
    float* ks   = ws + 32768;                 // 32768
    float* kmx  = ws + 65536;                 // 16
    float* kmn  = ws + 65552;                 // 16
    unsigned short* vT = (unsigned short*)(ws + 65568);   // 2,097,152 bf16
    float* zpre = ws + 65568 + 1048576;       // 2,097,152 floats
    // Zb OVERLAYS vT: vT is dead after attn_kernel; stream order makes this
    // deterministic (qkvT writes vT -> attn reads vT -> ln1 overwrites as Zb).
    unsigned short* Zb  = vT;                               // 2,097,152 bf16
    unsigned short* WbT = (unsigned short*)(ws + 65568 + 1048576 + 2097152); // 262,144 bf16

    qkvT_kernel<<<(B*T/64)*H, 256, 0, stream>>>(emb, qryk, keyk, valk, qs, ks, vT);
    minmax_kernel<<<B*H, 256, 0, stream>>>(ks, kmx, kmn);
    attn_kernel<<<B*H*(T/64), 256, 0, stream>>>(qs, ks, kmx, kmn, vT, emb, zpre);
    ln1_kernel<<<B*H*T/4, 256, 0, stream>>>(zpre, g1, b1, Zb);
    wcvt_kernel<<<H*H, 256, 0, stream>>>(ffk, WbT);
    ffn_gemm_kernel<<<(B*T/64)*H, 256, 0, stream>>>(Zb, WbT, g2, b2, out);
}